// Round 5
// baseline (2638.512 us; speedup 1.0000x reference)
//
#include <hip/hip_runtime.h>

// ---------------------------------------------------------------------------
// GraphSAGE 2-layer, bf16, deterministic bucket partition + LDS-accumulator
// aggregation (no csr materialization, no global atomics anywhere):
//   hist2:      per-8192-edge chunk LDS histogram of dst>>6 -> cntmat row
//   colscan:    per-bucket column scan of cntmat -> per-chunk prefixes+totals
//   bucket_scan: exclusive scan of totals -> bucket bases
//   partition2: LDS cursors = base+prefix, LDS-atomic scatter of packed
//               pairs ((dst&63)<<16 | src) into bucket ranges
//   prep:       xb = bf16(x); WT* = bf16(W^T)  (one kernel)
//   agg_bucket: 1 block per 32-node half-bucket, fp32 LDS accumulators,
//               in-kernel degree count -> mean  (layer1: bf16 out;
//               layer2: d_out += mean, in place)
//   gemm_l1:    hb = bf16(relu(mean1@Wl1 + xb@Wr1 + bl1))      (MFMA)
//   gemm_l2:    pb = bf16(hb@Wl2);  d_out = hb@Wr2 + bl2       (dual-B MFMA)
//   agg_bucket: d_out += mean(pb)   [projection-first: mean commutes]
// ---------------------------------------------------------------------------

#define IN_DIM 128
#define HID_DIM 256
#define OUT_DIM 128

#define EPB 8192   // edges per chunk
#define NBMAX 784  // max buckets (50000/64 -> 782)
#define CAP 2048   // staged pairs per agg chunk

typedef unsigned short u16;
typedef unsigned int u32;
typedef __attribute__((ext_vector_type(8))) short short8;   // 8 bf16 (4 VGPRs)
typedef __attribute__((ext_vector_type(4))) float float4v;  // 4 fp32 acc

static __device__ __forceinline__ u16 f2bf(float f) {
    u32 u = __builtin_bit_cast(u32, f);
    u = (u + 0x7fffu + ((u >> 16) & 1u)) >> 16;
    return (u16)u;
}
static __device__ __forceinline__ float bf2f(u32 lo16) {
    return __builtin_bit_cast(float, lo16 << 16);
}

// -------------------- deterministic bucketed partition --------------------

__global__ __launch_bounds__(256) void hist2(const int* __restrict__ dst,
                                             int n_edges, int nb,
                                             int* __restrict__ cntmat) {
    __shared__ int h[NBMAX];
    int t = threadIdx.x;
    for (int i = t; i < nb; i += 256) h[i] = 0;
    __syncthreads();
    int base = blockIdx.x * EPB;
    int end = min(base + EPB, n_edges);
    for (int i = base + t; i < end; i += 256) atomicAdd(&h[dst[i] >> 6], 1);
    __syncthreads();
    int* row = cntmat + (size_t)blockIdx.x * nb;
    for (int i = t; i < nb; i += 256) row[i] = h[i];
}

__global__ __launch_bounds__(256) void colscan(int* __restrict__ cntmat,
                                               int nblk, int nb,
                                               int* __restrict__ bcnt) {
    int b = blockIdx.x * 256 + threadIdx.x;
    if (b >= nb) return;
    int run = 0;
    for (int blk = 0; blk < nblk; blk++) {
        size_t idx = (size_t)blk * nb + b;
        int v = cntmat[idx];
        cntmat[idx] = run;
        run += v;
    }
    bcnt[b] = run;
}

__global__ __launch_bounds__(1024) void bucket_scan(
    const int* __restrict__ bcnt, int nb, int n_edges,
    int* __restrict__ bbase) {
    __shared__ int s[1024];
    int t = threadIdx.x;
    int v = (t < nb) ? bcnt[t] : 0;
    s[t] = v;
    __syncthreads();
    for (int off = 1; off < 1024; off <<= 1) {
        int add = (t >= off) ? s[t - off] : 0;
        __syncthreads();
        s[t] += add;
        __syncthreads();
    }
    if (t < nb) bbase[t] = s[t] - v;
    if (t == 0) bbase[nb] = n_edges;
}

__global__ __launch_bounds__(256) void partition2(
    const int* __restrict__ src, const int* __restrict__ dst, int n_edges,
    int nb, const int* __restrict__ bbase, const int* __restrict__ cntmat,
    u32* __restrict__ pairs) {
    __shared__ int cur[NBMAX];
    int t = threadIdx.x;
    const int* row = cntmat + (size_t)blockIdx.x * nb;
    for (int i = t; i < nb; i += 256) cur[i] = bbase[i] + row[i];
    __syncthreads();
    int base = blockIdx.x * EPB;
    int end = min(base + EPB, n_edges);
    for (int i = base + t; i < end; i += 256) {
        int d = dst[i];
        int pos = atomicAdd(&cur[d >> 6], 1);  // LDS atomic
        pairs[pos] = ((u32)(d & 63) << 16) | (u32)src[i];
    }
}

// -------------------- prep: x cast + 4 weight transpose-casts -------------

__global__ __launch_bounds__(256) void prep_kernel(
    const float* __restrict__ x, u16* __restrict__ xb,
    const float* __restrict__ Wl1, const float* __restrict__ Wr1,
    const float* __restrict__ Wl2, const float* __restrict__ Wr2,
    u16* __restrict__ WTl1, u16* __restrict__ WTr1,
    u16* __restrict__ WTl2, u16* __restrict__ WTr2, int n4) {
    int i = blockIdx.x * 256 + threadIdx.x;
    if (i < n4) {
        float4 v = *(const float4*)(x + (size_t)i * 4);
        uint2 o;
        o.x = (u32)f2bf(v.x) | ((u32)f2bf(v.y) << 16);
        o.y = (u32)f2bf(v.z) | ((u32)f2bf(v.w) << 16);
        *(uint2*)(xb + (size_t)i * 4) = o;
        return;
    }
    int j = i - n4;
    if (j >= 4 * 32768) return;
    int seg = j >> 15;
    int r = j & 32767;
    // seg 0/1: W [128][256] -> WT [256][128]; seg 2/3: W [256][128] -> WT [128][256]
    if (seg == 0) WTl1[r] = f2bf(Wl1[(size_t)(r & 127) * 256 + (r >> 7)]);
    else if (seg == 1) WTr1[r] = f2bf(Wr1[(size_t)(r & 127) * 256 + (r >> 7)]);
    else if (seg == 2) WTl2[r] = f2bf(Wl2[(size_t)(r & 255) * 128 + (r >> 8)]);
    else WTr2[r] = f2bf(Wr2[(size_t)(r & 255) * 128 + (r >> 8)]);
}

// -------------------- LDS-accumulator mean aggregation --------------------
// 1 block per 32-node half-bucket (grid = nb*2). D = 128 bf16 features.
// Each half-wave processes its own edge: 2 dword gathers (dims 2l,2l+1 and
// 2l+64,2l+65), 4 ds_add_f32 into acc[node][129-padded].
// layer1 (out_bf != 0): write bf16 mean. layer2: inout_f[row] += mean.

__global__ __launch_bounds__(256) void agg_bucket(
    const u16* __restrict__ feat, const u32* __restrict__ pairs,
    const int* __restrict__ bbase, int n_nodes,
    u16* __restrict__ out_bf, float* __restrict__ inout_f) {
    __shared__ float acc[32][129];
    __shared__ u32 spair[CAP];
    __shared__ int cnt[32];
    int t = threadIdx.x;
    int b = blockIdx.x >> 1;
    int halfsel = blockIdx.x & 1;
    int node_base = b * 64 + halfsel * 32;
    for (int i = t; i < 32 * 129; i += 256) ((float*)acc)[i] = 0.f;
    if (t < 32) cnt[t] = 0;
    int beg = bbase[b], end = bbase[b + 1];
    int wave = t >> 6, lane = t & 63, half = lane >> 5, l32 = lane & 31;

    for (int base = beg; base < end; base += CAP) {
        int m = min(CAP, end - base);
        __syncthreads();  // protect spair reuse (also covers acc zero-init)
        for (int i = t; i < m; i += 256) {
            u32 pr = pairs[base + i];
            spair[i] = pr;
            int n = (pr >> 16) & 63;
            if ((n >> 5) == halfsel) atomicAdd(&cnt[n & 31], 1);
        }
        __syncthreads();
        int e0 = wave * 2 + half;
        for (int e = e0; e < m; e += 32) {  // unroll 4 x stride 8
            u32 pr[4], v0[4], v1[4];
            int n[4];
            bool own[4];
#pragma unroll
            for (int j = 0; j < 4; j++) {
                int ej = e + j * 8;
                bool valid = ej < m;
                pr[j] = valid ? spair[ej] : 0u;
                n[j] = (pr[j] >> 16) & 63;
                own[j] = valid && ((n[j] >> 5) == halfsel);
                if (own[j]) {
                    const u16* rp =
                        feat + ((size_t)(pr[j] & 0xffffu)) * 128 + l32 * 2;
                    v0[j] = *(const u32*)rp;
                    v1[j] = *(const u32*)(rp + 64);
                }
            }
#pragma unroll
            for (int j = 0; j < 4; j++) {
                if (own[j]) {
                    int nl = n[j] & 31;
                    atomicAdd(&acc[nl][2 * l32], bf2f(v0[j] & 0xffffu));
                    atomicAdd(&acc[nl][2 * l32 + 1], bf2f(v0[j] >> 16));
                    atomicAdd(&acc[nl][2 * l32 + 64], bf2f(v1[j] & 0xffffu));
                    atomicAdd(&acc[nl][2 * l32 + 65], bf2f(v1[j] >> 16));
                }
            }
        }
    }
    __syncthreads();
    // write: wave handles nodes wave*8..+7; lane covers dims {2*lane, 2*lane+1}
    for (int it = 0; it < 8; it++) {
        int nl = wave * 8 + it;
        int node = node_base + nl;
        if (node >= n_nodes) continue;
        int c = cnt[nl];
        float inv = 1.0f / (float)(c > 0 ? c : 1);
        float x0 = acc[nl][2 * lane] * inv;
        float x1 = acc[nl][2 * lane + 1] * inv;
        if (out_bf) {
            u32 pv = (u32)f2bf(x0) | ((u32)f2bf(x1) << 16);
            *(u32*)(out_bf + (size_t)node * 128 + lane * 2) = pv;
        } else {
            float2* q = (float2*)(inout_f + (size_t)node * 128 + lane * 2);
            float2 o = *q;
            o.x += x0;
            o.y += x1;
            *q = o;
        }
    }
}

// -------------------- MFMA GEMMs --------------------
// Frag layouts (verified m89/m91): A[m=lane&15][k=quad*8+j] from row-major,
// B-frags from B^T rows, C/D: col=lane&15, row=quad*4+reg.
// Block: 4 waves; tile 128(M) x 64(N); wave = 32x64 via 2x4 of 16x16x32.

// layer 1: hb = bf16(relu(mean1@Wl1 + xb@Wr1 + bl1)), K=128, N=256
__global__ __launch_bounds__(256) void gemm_l1(
    const u16* __restrict__ A1, const u16* __restrict__ A2,
    const u16* __restrict__ BT1, const u16* __restrict__ BT2,
    const float* __restrict__ bias, u16* __restrict__ out_bf, int M) {
    const int K = IN_DIM, N = HID_DIM, KP = K + 8;
    __shared__ u16 Bs[2 * 64 * (IN_DIM + 8)];
    int t = threadIdx.x;
    int colbase = blockIdx.y * 64;
    int total8 = 2 * 64 * K / 8;
    for (int c = t; c < total8; c += 256) {
        int flat = c * 8;
        int mat = flat / (64 * K);
        int rem = flat - mat * 64 * K;
        int n = rem / K, k = rem - n * K;
        const u16* srcp = (mat ? BT2 : BT1) + (size_t)(colbase + n) * K + k;
        *(uint4*)(&Bs[mat * 64 * KP + n * KP + k]) = *(const uint4*)srcp;
    }
    __syncthreads();

    int lane = t & 63, wave = t >> 6, quad = lane >> 4, l16 = lane & 15;
    int row_base = blockIdx.x * 128 + wave * 32;
    float4v zero = {0.f, 0.f, 0.f, 0.f};
    float4v acc[2][4];
#pragma unroll
    for (int mi = 0; mi < 2; mi++)
#pragma unroll
        for (int ni = 0; ni < 4; ni++) acc[mi][ni] = zero;

    for (int mat = 0; mat < 2; mat++) {
        const u16* A = mat ? A2 : A1;
        const u16* Bp = &Bs[mat * 64 * KP];
#pragma unroll
        for (int ks = 0; ks < K / 32; ks++) {
            int k = ks * 32 + quad * 8;
            short8 af[2] = {{0, 0, 0, 0, 0, 0, 0, 0}, {0, 0, 0, 0, 0, 0, 0, 0}};
#pragma unroll
            for (int mi = 0; mi < 2; mi++) {
                int m = row_base + mi * 16 + l16;
                if (m < M) af[mi] = *(const short8*)(A + (size_t)m * K + k);
            }
#pragma unroll
            for (int ni = 0; ni < 4; ni++) {
                short8 bfr = *(const short8*)(Bp + (ni * 16 + l16) * KP + k);
                acc[0][ni] = __builtin_amdgcn_mfma_f32_16x16x32_bf16(
                    af[0], bfr, acc[0][ni], 0, 0, 0);
                acc[1][ni] = __builtin_amdgcn_mfma_f32_16x16x32_bf16(
                    af[1], bfr, acc[1][ni], 0, 0, 0);
            }
        }
    }
#pragma unroll
    for (int mi = 0; mi < 2; mi++)
#pragma unroll
        for (int r = 0; r < 4; r++) {
            int row = row_base + mi * 16 + quad * 4 + r;
            if (row >= M) continue;
#pragma unroll
            for (int ni = 0; ni < 4; ni++) {
                int col = colbase + ni * 16 + l16;
                float v = acc[mi][ni][r] + bias[col];
                v = fmaxf(v, 0.f);
                out_bf[(size_t)row * N + col] = f2bf(v);
            }
        }
}

// layer 2 dual-B: pb = bf16(hb@Wl2); out = hb@Wr2 + bl2 (fp32). K=256, N=128
__global__ __launch_bounds__(256) void gemm_l2(
    const u16* __restrict__ A, const u16* __restrict__ BT1,
    const u16* __restrict__ BT2, const float* __restrict__ bias2,
    u16* __restrict__ out1_bf, float* __restrict__ out2_f, int M) {
    const int K = HID_DIM, N = OUT_DIM, KP = K + 8;
    __shared__ u16 Bs[2 * 64 * (HID_DIM + 8)];
    int t = threadIdx.x;
    int colbase = blockIdx.y * 64;
    int total8 = 2 * 64 * K / 8;
    for (int c = t; c < total8; c += 256) {
        int flat = c * 8;
        int mat = flat / (64 * K);
        int rem = flat - mat * 64 * K;
        int n = rem / K, k = rem - n * K;
        const u16* srcp = (mat ? BT2 : BT1) + (size_t)(colbase + n) * K + k;
        *(uint4*)(&Bs[mat * 64 * KP + n * KP + k]) = *(const uint4*)srcp;
    }
    __syncthreads();

    int lane = t & 63, wave = t >> 6, quad = lane >> 4, l16 = lane & 15;
    int row_base = blockIdx.x * 128 + wave * 32;
    float4v zero = {0.f, 0.f, 0.f, 0.f};
    float4v acc1[2][4], acc2[2][4];
#pragma unroll
    for (int mi = 0; mi < 2; mi++)
#pragma unroll
        for (int ni = 0; ni < 4; ni++) {
            acc1[mi][ni] = zero;
            acc2[mi][ni] = zero;
        }

#pragma unroll
    for (int ks = 0; ks < K / 32; ks++) {
        int k = ks * 32 + quad * 8;
        short8 af[2] = {{0, 0, 0, 0, 0, 0, 0, 0}, {0, 0, 0, 0, 0, 0, 0, 0}};
#pragma unroll
        for (int mi = 0; mi < 2; mi++) {
            int m = row_base + mi * 16 + l16;
            if (m < M) af[mi] = *(const short8*)(A + (size_t)m * K + k);
        }
#pragma unroll
        for (int ni = 0; ni < 4; ni++) {
            short8 b1 = *(const short8*)(&Bs[(ni * 16 + l16) * KP + k]);
            short8 b2 = *(const short8*)(&Bs[64 * KP + (ni * 16 + l16) * KP + k]);
            acc1[0][ni] = __builtin_amdgcn_mfma_f32_16x16x32_bf16(
                af[0], b1, acc1[0][ni], 0, 0, 0);
            acc1[1][ni] = __builtin_amdgcn_mfma_f32_16x16x32_bf16(
                af[1], b1, acc1[1][ni], 0, 0, 0);
            acc2[0][ni] = __builtin_amdgcn_mfma_f32_16x16x32_bf16(
                af[0], b2, acc2[0][ni], 0, 0, 0);
            acc2[1][ni] = __builtin_amdgcn_mfma_f32_16x16x32_bf16(
                af[1], b2, acc2[1][ni], 0, 0, 0);
        }
    }
#pragma unroll
    for (int mi = 0; mi < 2; mi++)
#pragma unroll
        for (int r = 0; r < 4; r++) {
            int row = row_base + mi * 16 + quad * 4 + r;
            if (row >= M) continue;
#pragma unroll
            for (int ni = 0; ni < 4; ni++) {
                int col = colbase + ni * 16 + l16;
                out1_bf[(size_t)row * N + col] = f2bf(acc1[mi][ni][r]);
                out2_f[(size_t)row * N + col] = acc2[mi][ni][r] + bias2[col];
            }
        }
}

// -------------------- launcher --------------------

extern "C" void kernel_launch(void* const* d_in, const int* in_sizes, int n_in,
                              void* d_out, int out_size, void* d_ws, size_t ws_size,
                              hipStream_t stream) {
    const float* x   = (const float*)d_in[0];
    const int*  eidx = (const int*)d_in[1];
    const float* Wl1 = (const float*)d_in[2];
    const float* bl1 = (const float*)d_in[3];
    const float* Wr1 = (const float*)d_in[4];
    const float* Wl2 = (const float*)d_in[5];
    const float* bl2 = (const float*)d_in[6];
    const float* Wr2 = (const float*)d_in[7];

    int n_nodes = in_sizes[0] / IN_DIM;
    int n_edges = in_sizes[1] / 2;
    const int* src = eidx;
    const int* dst = eidx + n_edges;
    int nb = (n_nodes + 63) / 64;            // buckets of 64 nodes
    int nchunk = (n_edges + EPB - 1) / EPB;  // edge chunks

    char* p = (char*)d_ws;
    auto alloc = [&](size_t bytes) {
        void* q = (void*)p;
        p += (bytes + 255) & ~(size_t)255;
        return q;
    };
    int*   bcnt   = (int*)alloc((size_t)(nb + 1) * 4);
    int*   bbase  = (int*)alloc((size_t)(nb + 1) * 4);
    int*   cntmat = (int*)alloc((size_t)nchunk * nb * 4);
    u32*   pairs  = (u32*)alloc((size_t)n_edges * 4);
    u16*   xb     = (u16*)alloc((size_t)n_nodes * IN_DIM * 2);
    u16*   mean1b = (u16*)alloc((size_t)n_nodes * IN_DIM * 2);
    u16*   hb     = (u16*)alloc((size_t)n_nodes * HID_DIM * 2);
    u16*   pb     = (u16*)alloc((size_t)n_nodes * OUT_DIM * 2);
    u16*   WTl1b  = (u16*)alloc((size_t)IN_DIM * HID_DIM * 2);
    u16*   WTr1b  = (u16*)alloc((size_t)IN_DIM * HID_DIM * 2);
    u16*   WTl2b  = (u16*)alloc((size_t)HID_DIM * OUT_DIM * 2);
    u16*   WTr2b  = (u16*)alloc((size_t)HID_DIM * OUT_DIM * 2);

    // bucketed partition (no global atomics)
    hist2<<<nchunk, 256, 0, stream>>>(dst, n_edges, nb, cntmat);
    colscan<<<(nb + 255) / 256, 256, 0, stream>>>(cntmat, nchunk, nb, bcnt);
    bucket_scan<<<1, 1024, 0, stream>>>(bcnt, nb, n_edges, bbase);
    partition2<<<nchunk, 256, 0, stream>>>(src, dst, n_edges, nb, bbase,
                                           cntmat, pairs);

    // casts (one kernel)
    int n4 = n_nodes * IN_DIM / 4;
    int prep_items = n4 + 4 * 32768;
    prep_kernel<<<(prep_items + 255) / 256, 256, 0, stream>>>(
        x, xb, Wl1, Wr1, Wl2, Wr2, WTl1b, WTr1b, WTl2b, WTr2b, n4);

    int gx = (n_nodes + 127) / 128;

    // layer 1
    agg_bucket<<<nb * 2, 256, 0, stream>>>(xb, pairs, bbase, n_nodes,
                                           mean1b, nullptr);
    {
        dim3 g(gx, HID_DIM / 64);
        gemm_l1<<<g, 256, 0, stream>>>(mean1b, xb, WTl1b, WTr1b, bl1, hb,
                                       n_nodes);
    }

    // layer 2: pb = hb@Wl2 ; d_out = hb@Wr2 + bl2  (one pass over hb)
    {
        dim3 g(gx, OUT_DIM / 64);
        gemm_l2<<<g, 256, 0, stream>>>(hb, WTl2b, WTr2b, bl2, pb,
                                       (float*)d_out, n_nodes);
    }
    // d_out += mean(pb)
    agg_bucket<<<nb * 2, 256, 0, stream>>>(pb, pairs, bbase, n_nodes,
                                           nullptr, (float*)d_out);
}

// Round 6
// 359.727 us; speedup vs baseline: 7.3348x; 7.3348x over previous
//
#include <hip/hip_runtime.h>

// ---------------------------------------------------------------------------
// GraphSAGE 2-layer, bf16. Pipeline (10 launches):
//   hist2:        per-8192-edge chunk LDS histogram of dst>>6 -> cntmat row
//   colscan:      per-bucket column scan of cntmat -> per-chunk prefixes+totals
//   bucket_scan:  exclusive scan of totals -> bucket bases
//   partition2:   LDS cursors = base+prefix, LDS-atomic scatter of packed
//                 pairs ((dst&63)<<16 | src) into bucket ranges
//   bucket_scatter: 1 wg/bucket, LDS node cursors -> offs/inv_deg/csr
//   prep:         xb = bf16(x); WT* = bf16(W^T)  (one kernel)
//   agg_bf16:     streaming mean-agg, 1 wave/node (VGPR accumulate)
//   gemm_l1:      hb = bf16(relu(mean1@Wl1 + xb@Wr1 + bl1))      (MFMA)
//   gemm_l2:      pb = bf16(hb@Wl2);  d_out = hb@Wr2 + bl2       (dual-B MFMA)
//   agg_bf16:     d_out += mean(pb)   [projection-first: mean commutes]
// NOTE (R4 post-mortem): LDS-accumulator agg (agg_bucket) was 20x SLOWER than
// the streaming wave-per-node agg — LDS fp32 atomics + divergence serialize.
// Do not revisit.
// ---------------------------------------------------------------------------

#define IN_DIM 128
#define HID_DIM 256
#define OUT_DIM 128

#define EPB 8192   // edges per chunk
#define NBMAX 784  // max buckets (50000/64 -> 782)

typedef unsigned short u16;
typedef unsigned int u32;
typedef __attribute__((ext_vector_type(8))) short short8;   // 8 bf16 (4 VGPRs)
typedef __attribute__((ext_vector_type(4))) float float4v;  // 4 fp32 acc

static __device__ __forceinline__ u16 f2bf(float f) {
    u32 u = __builtin_bit_cast(u32, f);
    u = (u + 0x7fffu + ((u >> 16) & 1u)) >> 16;
    return (u16)u;
}
static __device__ __forceinline__ float bf2f(u32 lo16) {
    return __builtin_bit_cast(float, lo16 << 16);
}

// -------------------- deterministic bucketed partition --------------------

__global__ __launch_bounds__(256) void hist2(const int* __restrict__ dst,
                                             int n_edges, int nb,
                                             int* __restrict__ cntmat) {
    __shared__ int h[NBMAX];
    int t = threadIdx.x;
    for (int i = t; i < nb; i += 256) h[i] = 0;
    __syncthreads();
    int base = blockIdx.x * EPB;
    int end = min(base + EPB, n_edges);
    for (int i = base + t; i < end; i += 256) atomicAdd(&h[dst[i] >> 6], 1);
    __syncthreads();
    int* row = cntmat + (size_t)blockIdx.x * nb;
    for (int i = t; i < nb; i += 256) row[i] = h[i];
}

__global__ __launch_bounds__(256) void colscan(int* __restrict__ cntmat,
                                               int nblk, int nb,
                                               int* __restrict__ bcnt) {
    int b = blockIdx.x * 256 + threadIdx.x;
    if (b >= nb) return;
    int run = 0;
    for (int blk = 0; blk < nblk; blk++) {
        size_t idx = (size_t)blk * nb + b;
        int v = cntmat[idx];
        cntmat[idx] = run;
        run += v;
    }
    bcnt[b] = run;
}

__global__ __launch_bounds__(1024) void bucket_scan(
    const int* __restrict__ bcnt, int nb, int n_edges,
    int* __restrict__ bbase) {
    __shared__ int s[1024];
    int t = threadIdx.x;
    int v = (t < nb) ? bcnt[t] : 0;
    s[t] = v;
    __syncthreads();
    for (int off = 1; off < 1024; off <<= 1) {
        int add = (t >= off) ? s[t - off] : 0;
        __syncthreads();
        s[t] += add;
        __syncthreads();
    }
    if (t < nb) bbase[t] = s[t] - v;
    if (t == 0) bbase[nb] = n_edges;
}

__global__ __launch_bounds__(256) void partition2(
    const int* __restrict__ src, const int* __restrict__ dst, int n_edges,
    int nb, const int* __restrict__ bbase, const int* __restrict__ cntmat,
    u32* __restrict__ pairs) {
    __shared__ int cur[NBMAX];
    int t = threadIdx.x;
    const int* row = cntmat + (size_t)blockIdx.x * nb;
    for (int i = t; i < nb; i += 256) cur[i] = bbase[i] + row[i];
    __syncthreads();
    int base = blockIdx.x * EPB;
    int end = min(base + EPB, n_edges);
    for (int i = base + t; i < end; i += 256) {
        int d = dst[i];
        int pos = atomicAdd(&cur[d >> 6], 1);  // LDS atomic
        pairs[pos] = ((u32)(d & 63) << 16) | (u32)src[i];
    }
}

__global__ __launch_bounds__(256) void bucket_scatter(
    const u32* __restrict__ pairs, const int* __restrict__ bbase,
    int n_nodes, int n_edges,
    int* __restrict__ offs, float* __restrict__ inv_deg,
    int* __restrict__ csr) {
    int b = blockIdx.x;
    int t = threadIdx.x;
    int beg = bbase[b], end = bbase[b + 1];
    __shared__ int cnt[64];
    __shared__ int cur[64];
    if (t < 64) cnt[t] = 0;
    __syncthreads();
    for (int i = beg + t; i < end; i += 256)
        atomicAdd(&cnt[(pairs[i] >> 16) & 63], 1);
    __syncthreads();
    if (t < 64) {  // wave 0: shuffle exclusive scan over 64 node counts
        int v = cnt[t];
        int incl = v;
#pragma unroll
        for (int off = 1; off < 64; off <<= 1) {
            int u = __shfl_up(incl, off, 64);
            if (t >= off) incl += u;
        }
        int o = beg + incl - v;
        int node = b * 64 + t;
        if (node < n_nodes) {
            offs[node] = o;
            inv_deg[node] = 1.0f / (float)(v > 0 ? v : 1);
        }
        cur[t] = o;
    }
    if (b == 0 && t == 0) offs[n_nodes] = n_edges;
    __syncthreads();
    for (int i = beg + t; i < end; i += 256) {
        u32 pr = pairs[i];
        int p = atomicAdd(&cur[(pr >> 16) & 63], 1);
        csr[p] = (int)(pr & 0xffffu);
    }
}

// -------------------- prep: x cast + 4 weight transpose-casts -------------

__global__ __launch_bounds__(256) void prep_kernel(
    const float* __restrict__ x, u16* __restrict__ xb,
    const float* __restrict__ Wl1, const float* __restrict__ Wr1,
    const float* __restrict__ Wl2, const float* __restrict__ Wr2,
    u16* __restrict__ WTl1, u16* __restrict__ WTr1,
    u16* __restrict__ WTl2, u16* __restrict__ WTr2, int n4) {
    int i = blockIdx.x * 256 + threadIdx.x;
    if (i < n4) {
        float4 v = *(const float4*)(x + (size_t)i * 4);
        uint2 o;
        o.x = (u32)f2bf(v.x) | ((u32)f2bf(v.y) << 16);
        o.y = (u32)f2bf(v.z) | ((u32)f2bf(v.w) << 16);
        *(uint2*)(xb + (size_t)i * 4) = o;
        return;
    }
    int j = i - n4;
    if (j >= 4 * 32768) return;
    int seg = j >> 15;
    int r = j & 32767;
    // seg 0/1: W [128][256] -> WT [256][128]; seg 2/3: W [256][128] -> WT [128][256]
    if (seg == 0) WTl1[r] = f2bf(Wl1[(size_t)(r & 127) * 256 + (r >> 7)]);
    else if (seg == 1) WTr1[r] = f2bf(Wr1[(size_t)(r & 127) * 256 + (r >> 7)]);
    else if (seg == 2) WTl2[r] = f2bf(Wl2[(size_t)(r & 255) * 128 + (r >> 8)]);
    else WTr2[r] = f2bf(Wr2[(size_t)(r & 255) * 128 + (r >> 8)]);
}

// -------------------- mean aggregation (D=128 bf16, 1 wave/node) -----------
// out_bf != 0: write bf16 mean.  else: out_f[row] += mean (in-place fp32).

__global__ __launch_bounds__(256) void agg_bf16(
    const u16* __restrict__ feat, const int* __restrict__ offs,
    const int* __restrict__ csr, const float* __restrict__ inv_deg,
    int n_nodes, u16* __restrict__ out_bf, float* __restrict__ out_f) {
    int wave = threadIdx.x >> 6;
    int lane = threadIdx.x & 63;
    int node = blockIdx.x * 4 + wave;
    if (node >= n_nodes) return;
    int beg = offs[node], end = offs[node + 1];
    float a0 = 0.f, a1 = 0.f;
    int i = beg;
    for (; i + 8 <= end; i += 8) {
        u32 v[8];
#pragma unroll
        for (int j = 0; j < 8; j++) {
            int s = csr[i + j];
            v[j] = *(const u32*)(feat + (size_t)s * 128 + lane * 2);
        }
#pragma unroll
        for (int j = 0; j < 8; j++) {
            a0 += bf2f(v[j] & 0xffffu);
            a1 += bf2f(v[j] >> 16);
        }
    }
    for (; i < end; i++) {
        int s = csr[i];
        u32 v = *(const u32*)(feat + (size_t)s * 128 + lane * 2);
        a0 += bf2f(v & 0xffffu);
        a1 += bf2f(v >> 16);
    }
    float inv = inv_deg[node];
    a0 *= inv;
    a1 *= inv;
    if (out_bf) {
        u32 pv = (u32)f2bf(a0) | ((u32)f2bf(a1) << 16);
        *(u32*)(out_bf + (size_t)node * 128 + lane * 2) = pv;
    } else {
        float2* q = (float2*)(out_f + (size_t)node * 128 + lane * 2);
        float2 o = *q;
        o.x += a0;
        o.y += a1;
        *q = o;
    }
}

// -------------------- MFMA GEMMs --------------------
// Frag layouts (verified m89/m91): A[m=lane&15][k=quad*8+j] from row-major,
// B-frags from B^T rows, C/D: col=lane&15, row=quad*4+reg.
// Block: 4 waves; tile 128(M) x 64(N); wave = 32x64 via 2x4 of 16x16x32.

// layer 1: hb = bf16(relu(mean1@Wl1 + xb@Wr1 + bl1)), K=128, N=256
__global__ __launch_bounds__(256) void gemm_l1(
    const u16* __restrict__ A1, const u16* __restrict__ A2,
    const u16* __restrict__ BT1, const u16* __restrict__ BT2,
    const float* __restrict__ bias, u16* __restrict__ out_bf, int M) {
    const int K = IN_DIM, N = HID_DIM, KP = K + 8;
    __shared__ u16 Bs[2 * 64 * (IN_DIM + 8)];
    int t = threadIdx.x;
    int colbase = blockIdx.y * 64;
    int total8 = 2 * 64 * K / 8;
    for (int c = t; c < total8; c += 256) {
        int flat = c * 8;
        int mat = flat / (64 * K);
        int rem = flat - mat * 64 * K;
        int n = rem / K, k = rem - n * K;
        const u16* srcp = (mat ? BT2 : BT1) + (size_t)(colbase + n) * K + k;
        *(uint4*)(&Bs[mat * 64 * KP + n * KP + k]) = *(const uint4*)srcp;
    }
    __syncthreads();

    int lane = t & 63, wave = t >> 6, quad = lane >> 4, l16 = lane & 15;
    int row_base = blockIdx.x * 128 + wave * 32;
    float4v zero = {0.f, 0.f, 0.f, 0.f};
    float4v acc[2][4];
#pragma unroll
    for (int mi = 0; mi < 2; mi++)
#pragma unroll
        for (int ni = 0; ni < 4; ni++) acc[mi][ni] = zero;

    for (int mat = 0; mat < 2; mat++) {
        const u16* A = mat ? A2 : A1;
        const u16* Bp = &Bs[mat * 64 * KP];
#pragma unroll
        for (int ks = 0; ks < K / 32; ks++) {
            int k = ks * 32 + quad * 8;
            short8 af[2] = {{0, 0, 0, 0, 0, 0, 0, 0}, {0, 0, 0, 0, 0, 0, 0, 0}};
#pragma unroll
            for (int mi = 0; mi < 2; mi++) {
                int m = row_base + mi * 16 + l16;
                if (m < M) af[mi] = *(const short8*)(A + (size_t)m * K + k);
            }
#pragma unroll
            for (int ni = 0; ni < 4; ni++) {
                short8 bfr = *(const short8*)(Bp + (ni * 16 + l16) * KP + k);
                acc[0][ni] = __builtin_amdgcn_mfma_f32_16x16x32_bf16(
                    af[0], bfr, acc[0][ni], 0, 0, 0);
                acc[1][ni] = __builtin_amdgcn_mfma_f32_16x16x32_bf16(
                    af[1], bfr, acc[1][ni], 0, 0, 0);
            }
        }
    }
#pragma unroll
    for (int mi = 0; mi < 2; mi++)
#pragma unroll
        for (int r = 0; r < 4; r++) {
            int row = row_base + mi * 16 + quad * 4 + r;
            if (row >= M) continue;
#pragma unroll
            for (int ni = 0; ni < 4; ni++) {
                int col = colbase + ni * 16 + l16;
                float v = acc[mi][ni][r] + bias[col];
                v = fmaxf(v, 0.f);
                out_bf[(size_t)row * N + col] = f2bf(v);
            }
        }
}

// layer 2 dual-B: pb = bf16(hb@Wl2); out = hb@Wr2 + bl2 (fp32). K=256, N=128
__global__ __launch_bounds__(256) void gemm_l2(
    const u16* __restrict__ A, const u16* __restrict__ BT1,
    const u16* __restrict__ BT2, const float* __restrict__ bias2,
    u16* __restrict__ out1_bf, float* __restrict__ out2_f, int M) {
    const int K = HID_DIM, N = OUT_DIM, KP = K + 8;
    __shared__ u16 Bs[2 * 64 * (HID_DIM + 8)];
    int t = threadIdx.x;
    int colbase = blockIdx.y * 64;
    int total8 = 2 * 64 * K / 8;
    for (int c = t; c < total8; c += 256) {
        int flat = c * 8;
        int mat = flat / (64 * K);
        int rem = flat - mat * 64 * K;
        int n = rem / K, k = rem - n * K;
        const u16* srcp = (mat ? BT2 : BT1) + (size_t)(colbase + n) * K + k;
        *(uint4*)(&Bs[mat * 64 * KP + n * KP + k]) = *(const uint4*)srcp;
    }
    __syncthreads();

    int lane = t & 63, wave = t >> 6, quad = lane >> 4, l16 = lane & 15;
    int row_base = blockIdx.x * 128 + wave * 32;
    float4v zero = {0.f, 0.f, 0.f, 0.f};
    float4v acc1[2][4], acc2[2][4];
#pragma unroll
    for (int mi = 0; mi < 2; mi++)
#pragma unroll
        for (int ni = 0; ni < 4; ni++) {
            acc1[mi][ni] = zero;
            acc2[mi][ni] = zero;
        }

#pragma unroll
    for (int ks = 0; ks < K / 32; ks++) {
        int k = ks * 32 + quad * 8;
        short8 af[2] = {{0, 0, 0, 0, 0, 0, 0, 0}, {0, 0, 0, 0, 0, 0, 0, 0}};
#pragma unroll
        for (int mi = 0; mi < 2; mi++) {
            int m = row_base + mi * 16 + l16;
            if (m < M) af[mi] = *(const short8*)(A + (size_t)m * K + k);
        }
#pragma unroll
        for (int ni = 0; ni < 4; ni++) {
            short8 b1 = *(const short8*)(&Bs[(ni * 16 + l16) * KP + k]);
            short8 b2 = *(const short8*)(&Bs[64 * KP + (ni * 16 + l16) * KP + k]);
            acc1[0][ni] = __builtin_amdgcn_mfma_f32_16x16x32_bf16(
                af[0], b1, acc1[0][ni], 0, 0, 0);
            acc1[1][ni] = __builtin_amdgcn_mfma_f32_16x16x32_bf16(
                af[1], b1, acc1[1][ni], 0, 0, 0);
            acc2[0][ni] = __builtin_amdgcn_mfma_f32_16x16x32_bf16(
                af[0], b2, acc2[0][ni], 0, 0, 0);
            acc2[1][ni] = __builtin_amdgcn_mfma_f32_16x16x32_bf16(
                af[1], b2, acc2[1][ni], 0, 0, 0);
        }
    }
#pragma unroll
    for (int mi = 0; mi < 2; mi++)
#pragma unroll
        for (int r = 0; r < 4; r++) {
            int row = row_base + mi * 16 + quad * 4 + r;
            if (row >= M) continue;
#pragma unroll
            for (int ni = 0; ni < 4; ni++) {
                int col = colbase + ni * 16 + l16;
                out1_bf[(size_t)row * N + col] = f2bf(acc1[mi][ni][r]);
                out2_f[(size_t)row * N + col] = acc2[mi][ni][r] + bias2[col];
            }
        }
}

// -------------------- launcher --------------------

extern "C" void kernel_launch(void* const* d_in, const int* in_sizes, int n_in,
                              void* d_out, int out_size, void* d_ws, size_t ws_size,
                              hipStream_t stream) {
    const float* x   = (const float*)d_in[0];
    const int*  eidx = (const int*)d_in[1];
    const float* Wl1 = (const float*)d_in[2];
    const float* bl1 = (const float*)d_in[3];
    const float* Wr1 = (const float*)d_in[4];
    const float* Wl2 = (const float*)d_in[5];
    const float* bl2 = (const float*)d_in[6];
    const float* Wr2 = (const float*)d_in[7];

    int n_nodes = in_sizes[0] / IN_DIM;
    int n_edges = in_sizes[1] / 2;
    const int* src = eidx;
    const int* dst = eidx + n_edges;
    int nb = (n_nodes + 63) / 64;            // buckets of 64 nodes
    int nchunk = (n_edges + EPB - 1) / EPB;  // edge chunks

    char* p = (char*)d_ws;
    auto alloc = [&](size_t bytes) {
        void* q = (void*)p;
        p += (bytes + 255) & ~(size_t)255;
        return q;
    };
    int*   bcnt    = (int*)alloc((size_t)(nb + 1) * 4);
    int*   bbase   = (int*)alloc((size_t)(nb + 1) * 4);
    int*   cntmat  = (int*)alloc((size_t)nchunk * nb * 4);
    int*   offs    = (int*)alloc((size_t)(n_nodes + 1) * 4);
    float* inv_deg = (float*)alloc((size_t)n_nodes * 4);
    u32*   pairs   = (u32*)alloc((size_t)n_edges * 4);
    int*   csr     = (int*)alloc((size_t)n_edges * 4);
    u16*   xb      = (u16*)alloc((size_t)n_nodes * IN_DIM * 2);
    u16*   mean1b  = (u16*)alloc((size_t)n_nodes * IN_DIM * 2);
    u16*   hb      = (u16*)alloc((size_t)n_nodes * HID_DIM * 2);
    u16*   pb      = (u16*)alloc((size_t)n_nodes * OUT_DIM * 2);
    u16*   WTl1b   = (u16*)alloc((size_t)IN_DIM * HID_DIM * 2);
    u16*   WTr1b   = (u16*)alloc((size_t)IN_DIM * HID_DIM * 2);
    u16*   WTl2b   = (u16*)alloc((size_t)HID_DIM * OUT_DIM * 2);
    u16*   WTr2b   = (u16*)alloc((size_t)HID_DIM * OUT_DIM * 2);

    // bucketed CSR build (no global atomics)
    hist2<<<nchunk, 256, 0, stream>>>(dst, n_edges, nb, cntmat);
    colscan<<<(nb + 255) / 256, 256, 0, stream>>>(cntmat, nchunk, nb, bcnt);
    bucket_scan<<<1, 1024, 0, stream>>>(bcnt, nb, n_edges, bbase);
    partition2<<<nchunk, 256, 0, stream>>>(src, dst, n_edges, nb, bbase,
                                           cntmat, pairs);
    bucket_scatter<<<nb, 256, 0, stream>>>(pairs, bbase, n_nodes, n_edges,
                                           offs, inv_deg, csr);

    // casts (one kernel)
    int n4 = n_nodes * IN_DIM / 4;
    int prep_items = n4 + 4 * 32768;
    prep_kernel<<<(prep_items + 255) / 256, 256, 0, stream>>>(
        x, xb, Wl1, Wr1, Wl2, Wr2, WTl1b, WTr1b, WTl2b, WTr2b, n4);

    int gx = (n_nodes + 127) / 128;

    // layer 1
    agg_bf16<<<(n_nodes + 3) / 4, 256, 0, stream>>>(xb, offs, csr, inv_deg,
                                                    n_nodes, mean1b, nullptr);
    {
        dim3 g(gx, HID_DIM / 64);
        gemm_l1<<<g, 256, 0, stream>>>(mean1b, xb, WTl1b, WTr1b, bl1, hb,
                                       n_nodes);
    }

    // layer 2: pb = hb@Wl2 ; d_out = hb@Wr2 + bl2  (one pass over hb)
    {
        dim3 g(gx, OUT_DIM / 64);
        gemm_l2<<<g, 256, 0, stream>>>(hb, WTl2b, WTr2b, bl2, pb,
                                       (float*)d_out, n_nodes);
    }
    // d_out += mean(pb)
    agg_bf16<<<(n_nodes + 3) / 4, 256, 0, stream>>>(pb, offs, csr, inv_deg,
                                                    n_nodes, nullptr,
                                                    (float*)d_out);
}

// Round 8
// 326.744 us; speedup vs baseline: 8.0752x; 1.1009x over previous
//
#include <hip/hip_runtime.h>

// ---------------------------------------------------------------------------
// GraphSAGE 2-layer, bf16 MFMA + fp8 gather features. Pipeline (9 launches):
//   hist_prep:    [grid-partitioned] per-chunk LDS hist of dst>>6 -> cntmat
//                 + xb=bf16(x), xq=fp8(x) + WT*=bf16(W^T)
//   colscan:      per-bucket column scan of cntmat -> per-chunk prefixes+totals
//   bucket_scan:  exclusive scan of totals -> bucket bases
//   partition2:   LDS cursors = base+prefix, LDS-atomic scatter of packed
//                 pairs ((dst&63)<<16 | src) into bucket ranges
//   bucket_scatter: 1 wg/bucket, LDS node cursors -> offs/inv_deg/csr
//   agg_fp8:      streaming mean-agg of fp8 rows, 1 wave/node, half-wave/edge
//   gemm_l1:      hb = bf16(relu(mean1@Wl1 + xb@Wr1 + bl1))   (MFMA, bf16 A)
//   gemm_l2:      pbq = fp8(hb@Wl2);  d_out = hb@Wr2 + bl2    (dual-B MFMA)
//   agg_fp8:      d_out += mean(pbq)  [projection-first: mean commutes]
// NOTES:
//  - R4 post-mortem: LDS-accumulator agg was 20x slower (LDS fp32 atomics +
//    divergence serialize). Streaming wave-per-node agg is the right shape.
//  - R6: agg FETCH_SIZE=162MB on a 12.8MB set = per-XCD L2 thrash from L3;
//    fp8 halves bytes + fits ~L2. GEMM grids are (colstrip, rowblock) so
//    same-row col-blocks are adjacent in dispatch -> A re-reads hit L2.
//  - fp8 only on aggregated operands (noise averages down by sqrt(deg) and
//    passes through 0.05-scale weights); GEMM A/B stay bf16.
//  - R7: cvt_pk_*_fp8 'hi'/'old-sel' operand must be an immediate ->
//    helpers templated on HI.
// ---------------------------------------------------------------------------

#define IN_DIM 128
#define HID_DIM 256
#define OUT_DIM 128

#define EPB 8192   // edges per chunk
#define NBMAX 784  // max buckets (50000/64 -> 782)

typedef unsigned short u16;
typedef unsigned int u32;
typedef unsigned char u8;
typedef __attribute__((ext_vector_type(8))) short short8;   // 8 bf16 (4 VGPRs)
typedef __attribute__((ext_vector_type(4))) float float4v;  // 4 fp32 acc
typedef __attribute__((ext_vector_type(2))) float float2v;

#if defined(__has_builtin)
#if __has_builtin(__builtin_amdgcn_cvt_pk_f32_fp8) && \
    __has_builtin(__builtin_amdgcn_cvt_pk_fp8_f32)
#define HAVE_HW_FP8 1
#endif
#endif

static __device__ __forceinline__ u16 f2bf(float f) {
    u32 u = __builtin_bit_cast(u32, f);
    u = (u + 0x7fffu + ((u >> 16) & 1u)) >> 16;
    return (u16)u;
}
static __device__ __forceinline__ float bf2f(u32 lo16) {
    return __builtin_bit_cast(float, lo16 << 16);
}

#if !defined(HAVE_HW_FP8)
// manual OCP e4m3 decode (handles denormals; NaN not expected in data)
static __device__ __forceinline__ float fp8_dec1(u32 v) {
    u32 s = (v & 0x80u) << 24;
    u32 e = (v >> 3) & 0xFu;
    u32 m = v & 7u;
    float mag = e ? __builtin_bit_cast(float, ((e + 120u) << 23) | (m << 20))
                  : (float)m * 0x1p-9f;
    return __builtin_bit_cast(float, __builtin_bit_cast(u32, mag) | s);
}
// manual OCP e4m3 encode, RNE, saturate to +-448
static __device__ __forceinline__ u32 fp8_enc1(float f) {
    u32 u = __builtin_bit_cast(u32, f);
    u32 s = (u >> 24) & 0x80u;
    float af = fabsf(f);
    if (af > 448.f) af = 448.f;
    u32 a = __builtin_bit_cast(u32, af);
    int e = (int)((a >> 23) & 0xFF) - 127;
    u32 q;
    if (af < 0x1p-10f) q = 0;
    else if (e < -6) {
        q = (u32)__builtin_rintf(af * 512.f);
    } else {
        u32 m = a & 0x7FFFFFu;
        u32 r = m >> 20;
        u32 rem = m & 0xFFFFFu;
        if (rem > 0x80000u || (rem == 0x80000u && (r & 1u))) r++;
        u32 ee = (u32)(e + 7);
        if (r == 8u) { r = 0; ee++; }
        if (ee >= 16u) { ee = 15u; r = 6u; }
        q = (ee << 3) | r;
    }
    return s | q;
}
#endif

// decode 2 fp8 (low or high 16 bits of dword) -> 2 f32.  HI is an immediate.
template <bool HI>
static __device__ __forceinline__ float2v fp8pk2f(u32 w) {
#if defined(HAVE_HW_FP8)
    return __builtin_amdgcn_cvt_pk_f32_fp8(w, HI);
#else
    float2v r;
    u32 b0 = HI ? ((w >> 16) & 0xFFu) : (w & 0xFFu);
    u32 b1 = HI ? (w >> 24) : ((w >> 8) & 0xFFu);
    r.x = fp8_dec1(b0);
    r.y = fp8_dec1(b1);
    return r;
#endif
}
// pack 2 f32 -> 2 fp8 into selected 16-bit word of old.  HI is an immediate.
template <bool HI>
static __device__ __forceinline__ u32 f2fp8pk(float a, float b, u32 old) {
#if defined(HAVE_HW_FP8)
    return (u32)__builtin_amdgcn_cvt_pk_fp8_f32(a, b, (int)old, HI);
#else
    u32 pk = fp8_enc1(a) | (fp8_enc1(b) << 8);
    return HI ? ((old & 0x0000FFFFu) | (pk << 16))
              : ((old & 0xFFFF0000u) | pk);
#endif
}
static __device__ __forceinline__ u8 f2fp8_1(float v) {
    return (u8)(f2fp8pk<false>(v, v, 0u) & 0xFFu);
}

// -------------------- fused hist + casts (grid-partitioned) ---------------

__global__ __launch_bounds__(256) void hist_prep(
    const int* __restrict__ dst, int n_edges, int nb, int nchunk,
    int* __restrict__ cntmat,
    const float* __restrict__ x, u16* __restrict__ xb, u32* __restrict__ xq,
    const float* __restrict__ Wl1, const float* __restrict__ Wr1,
    const float* __restrict__ Wl2, const float* __restrict__ Wr2,
    u16* __restrict__ WTl1, u16* __restrict__ WTr1,
    u16* __restrict__ WTl2, u16* __restrict__ WTr2, int n4, int xblocks) {
    __shared__ int h[NBMAX];
    int b = blockIdx.x;
    int t = threadIdx.x;
    if (b < nchunk) {
        for (int i = t; i < nb; i += 256) h[i] = 0;
        __syncthreads();
        int base = b * EPB;
        int end = min(base + EPB, n_edges);
        for (int i = base + t; i < end; i += 256) atomicAdd(&h[dst[i] >> 6], 1);
        __syncthreads();
        int* row = cntmat + (size_t)b * nb;
        for (int i = t; i < nb; i += 256) row[i] = h[i];
        return;
    }
    if (b < nchunk + xblocks) {
        int i = (b - nchunk) * 256 + t;
        if (i < n4) {
            float4 v = *(const float4*)(x + (size_t)i * 4);
            uint2 o;
            o.x = (u32)f2bf(v.x) | ((u32)f2bf(v.y) << 16);
            o.y = (u32)f2bf(v.z) | ((u32)f2bf(v.w) << 16);
            *(uint2*)(xb + (size_t)i * 4) = o;
            u32 q = f2fp8pk<false>(v.x, v.y, 0u);
            q = f2fp8pk<true>(v.z, v.w, q);
            xq[i] = q;
        }
        return;
    }
    int j = (b - nchunk - xblocks) * 256 + t;
    if (j >= 4 * 32768) return;
    int seg = j >> 15;
    int r = j & 32767;
    // seg 0/1: W [128][256] -> WT [256][128]; seg 2/3: W [256][128] -> WT [128][256]
    if (seg == 0) WTl1[r] = f2bf(Wl1[(size_t)(r & 127) * 256 + (r >> 7)]);
    else if (seg == 1) WTr1[r] = f2bf(Wr1[(size_t)(r & 127) * 256 + (r >> 7)]);
    else if (seg == 2) WTl2[r] = f2bf(Wl2[(size_t)(r & 255) * 128 + (r >> 8)]);
    else WTr2[r] = f2bf(Wr2[(size_t)(r & 255) * 128 + (r >> 8)]);
}

// -------------------- deterministic bucketed partition --------------------

__global__ __launch_bounds__(256) void colscan(int* __restrict__ cntmat,
                                               int nblk, int nb,
                                               int* __restrict__ bcnt) {
    int b = blockIdx.x * 256 + threadIdx.x;
    if (b >= nb) return;
    int run = 0;
    for (int blk = 0; blk < nblk; blk++) {
        size_t idx = (size_t)blk * nb + b;
        int v = cntmat[idx];
        cntmat[idx] = run;
        run += v;
    }
    bcnt[b] = run;
}

__global__ __launch_bounds__(1024) void bucket_scan(
    const int* __restrict__ bcnt, int nb, int n_edges,
    int* __restrict__ bbase) {
    __shared__ int s[1024];
    int t = threadIdx.x;
    int v = (t < nb) ? bcnt[t] : 0;
    s[t] = v;
    __syncthreads();
    for (int off = 1; off < 1024; off <<= 1) {
        int add = (t >= off) ? s[t - off] : 0;
        __syncthreads();
        s[t] += add;
        __syncthreads();
    }
    if (t < nb) bbase[t] = s[t] - v;
    if (t == 0) bbase[nb] = n_edges;
}

__global__ __launch_bounds__(256) void partition2(
    const int* __restrict__ src, const int* __restrict__ dst, int n_edges,
    int nb, const int* __restrict__ bbase, const int* __restrict__ cntmat,
    u32* __restrict__ pairs) {
    __shared__ int cur[NBMAX];
    int t = threadIdx.x;
    const int* row = cntmat + (size_t)blockIdx.x * nb;
    for (int i = t; i < nb; i += 256) cur[i] = bbase[i] + row[i];
    __syncthreads();
    int base = blockIdx.x * EPB;
    int end = min(base + EPB, n_edges);
    for (int i = base + t; i < end; i += 256) {
        int d = dst[i];
        int pos = atomicAdd(&cur[d >> 6], 1);  // LDS atomic
        pairs[pos] = ((u32)(d & 63) << 16) | (u32)src[i];
    }
}

__global__ __launch_bounds__(256) void bucket_scatter(
    const u32* __restrict__ pairs, const int* __restrict__ bbase,
    int n_nodes, int n_edges,
    int* __restrict__ offs, float* __restrict__ inv_deg,
    int* __restrict__ csr) {
    int b = blockIdx.x;
    int t = threadIdx.x;
    int beg = bbase[b], end = bbase[b + 1];
    __shared__ int cnt[64];
    __shared__ int cur[64];
    if (t < 64) cnt[t] = 0;
    __syncthreads();
    for (int i = beg + t; i < end; i += 256)
        atomicAdd(&cnt[(pairs[i] >> 16) & 63], 1);
    __syncthreads();
    if (t < 64) {  // wave 0: shuffle exclusive scan over 64 node counts
        int v = cnt[t];
        int incl = v;
#pragma unroll
        for (int off = 1; off < 64; off <<= 1) {
            int u = __shfl_up(incl, off, 64);
            if (t >= off) incl += u;
        }
        int o = beg + incl - v;
        int node = b * 64 + t;
        if (node < n_nodes) {
            offs[node] = o;
            inv_deg[node] = 1.0f / (float)(v > 0 ? v : 1);
        }
        cur[t] = o;
    }
    if (b == 0 && t == 0) offs[n_nodes] = n_edges;
    __syncthreads();
    for (int i = beg + t; i < end; i += 256) {
        u32 pr = pairs[i];
        int p = atomicAdd(&cur[(pr >> 16) & 63], 1);
        csr[p] = (int)(pr & 0xffffu);
    }
}

// -------------------- fp8 mean aggregation (1 wave/node) ------------------
// feat: fp8 rows, 32 dwords (=128 dims) per row. Half-wave per edge:
// lanes 0-31 edge i, lanes 32-63 edge i+1; lane covers dims l32*4..+3.
// out_bf != 0: write bf16 mean.  else: out_f[row] += mean (in-place fp32).

__global__ __launch_bounds__(256) void agg_fp8(
    const u32* __restrict__ feat, const int* __restrict__ offs,
    const int* __restrict__ csr, const float* __restrict__ inv_deg,
    int n_nodes, u16* __restrict__ out_bf, float* __restrict__ out_f) {
    int wave = threadIdx.x >> 6;
    int lane = threadIdx.x & 63;
    int node = blockIdx.x * 4 + wave;
    if (node >= n_nodes) return;
    int beg = offs[node], end = offs[node + 1];
    int half = lane >> 5, l32 = lane & 31;
    float a0 = 0.f, a1 = 0.f, a2 = 0.f, a3 = 0.f;
    int i = beg;
    for (; i + 8 <= end; i += 8) {  // 8 edges: 4 slots x 2 halves
        u32 w[4];
#pragma unroll
        for (int j = 0; j < 4; j++) {
            int s = csr[i + 2 * j + half];
            w[j] = feat[(size_t)s * 32 + l32];
        }
#pragma unroll
        for (int j = 0; j < 4; j++) {
            float2v lo = fp8pk2f<false>(w[j]);
            float2v hi = fp8pk2f<true>(w[j]);
            a0 += lo.x;
            a1 += lo.y;
            a2 += hi.x;
            a3 += hi.y;
        }
    }
    for (; i < end; i += 2) {  // tail: up to 2 edges per step
        bool on = (i + half) < end;
        u32 w = 0;
        if (on) {
            int s = csr[i + half];
            w = feat[(size_t)s * 32 + l32];
        }
        float2v lo = fp8pk2f<false>(w);
        float2v hi = fp8pk2f<true>(w);
        if (on) {
            a0 += lo.x;
            a1 += lo.y;
            a2 += hi.x;
            a3 += hi.y;
        }
    }
    // combine the two halves
    a0 += __shfl_xor(a0, 32);
    a1 += __shfl_xor(a1, 32);
    a2 += __shfl_xor(a2, 32);
    a3 += __shfl_xor(a3, 32);
    float inv = inv_deg[node];
    a0 *= inv;
    a1 *= inv;
    a2 *= inv;
    a3 *= inv;
    if (half == 0) {
        if (out_bf) {
            uint2 o;
            o.x = (u32)f2bf(a0) | ((u32)f2bf(a1) << 16);
            o.y = (u32)f2bf(a2) | ((u32)f2bf(a3) << 16);
            *(uint2*)(out_bf + (size_t)node * 128 + l32 * 4) = o;
        } else {
            float4* q = (float4*)(out_f + (size_t)node * 128 + l32 * 4);
            float4 o = *q;
            o.x += a0;
            o.y += a1;
            o.z += a2;
            o.w += a3;
            *q = o;
        }
    }
}

// -------------------- MFMA GEMMs --------------------
// Frag layouts (verified m89/m91): A[m=lane&15][k=quad*8+j] from row-major,
// B-frags from B^T rows, C/D: col=lane&15, row=quad*4+reg.
// Grid: (colstrip, rowblock) so same-row col-strips are dispatch-adjacent
// and A re-reads hit L2. Block: 4 waves; tile 128(M) x 64(N).

// layer 1: hb = bf16(relu(mean1@Wl1 + xb@Wr1 + bl1)), K=128, N=256
__global__ __launch_bounds__(256) void gemm_l1(
    const u16* __restrict__ A1, const u16* __restrict__ A2,
    const u16* __restrict__ BT1, const u16* __restrict__ BT2,
    const float* __restrict__ bias, u16* __restrict__ out_bf, int M) {
    const int K = IN_DIM, N = HID_DIM, KP = K + 8;
    __shared__ u16 Bs[2 * 64 * (IN_DIM + 8)];
    int t = threadIdx.x;
    int colbase = blockIdx.x * 64;
    int total8 = 2 * 64 * K / 8;
    for (int c = t; c < total8; c += 256) {
        int flat = c * 8;
        int mat = flat / (64 * K);
        int rem = flat - mat * 64 * K;
        int n = rem / K, k = rem - n * K;
        const u16* srcp = (mat ? BT2 : BT1) + (size_t)(colbase + n) * K + k;
        *(uint4*)(&Bs[mat * 64 * KP + n * KP + k]) = *(const uint4*)srcp;
    }
    __syncthreads();

    int lane = t & 63, wave = t >> 6, quad = lane >> 4, l16 = lane & 15;
    int row_base = blockIdx.y * 128 + wave * 32;
    float4v zero = {0.f, 0.f, 0.f, 0.f};
    float4v acc[2][4];
#pragma unroll
    for (int mi = 0; mi < 2; mi++)
#pragma unroll
        for (int ni = 0; ni < 4; ni++) acc[mi][ni] = zero;

    for (int mat = 0; mat < 2; mat++) {
        const u16* A = mat ? A2 : A1;
        const u16* Bp = &Bs[mat * 64 * KP];
#pragma unroll
        for (int ks = 0; ks < K / 32; ks++) {
            int k = ks * 32 + quad * 8;
            short8 af[2] = {{0, 0, 0, 0, 0, 0, 0, 0}, {0, 0, 0, 0, 0, 0, 0, 0}};
#pragma unroll
            for (int mi = 0; mi < 2; mi++) {
                int m = row_base + mi * 16 + l16;
                if (m < M) af[mi] = *(const short8*)(A + (size_t)m * K + k);
            }
#pragma unroll
            for (int ni = 0; ni < 4; ni++) {
                short8 bfr = *(const short8*)(Bp + (ni * 16 + l16) * KP + k);
                acc[0][ni] = __builtin_amdgcn_mfma_f32_16x16x32_bf16(
                    af[0], bfr, acc[0][ni], 0, 0, 0);
                acc[1][ni] = __builtin_amdgcn_mfma_f32_16x16x32_bf16(
                    af[1], bfr, acc[1][ni], 0, 0, 0);
            }
        }
    }
#pragma unroll
    for (int mi = 0; mi < 2; mi++)
#pragma unroll
        for (int r = 0; r < 4; r++) {
            int row = row_base + mi * 16 + quad * 4 + r;
            if (row >= M) continue;
#pragma unroll
            for (int ni = 0; ni < 4; ni++) {
                int col = colbase + ni * 16 + l16;
                float v = acc[mi][ni][r] + bias[col];
                v = fmaxf(v, 0.f);
                out_bf[(size_t)row * N + col] = f2bf(v);
            }
        }
}

// layer 2 dual-B: pbq = fp8(hb@Wl2); out = hb@Wr2 + bl2 (fp32). K=256, N=128
__global__ __launch_bounds__(256) void gemm_l2(
    const u16* __restrict__ A, const u16* __restrict__ BT1,
    const u16* __restrict__ BT2, const float* __restrict__ bias2,
    u8* __restrict__ out1_q, float* __restrict__ out2_f, int M) {
    const int K = HID_DIM, N = OUT_DIM, KP = K + 8;
    __shared__ u16 Bs[2 * 64 * (HID_DIM + 8)];
    int t = threadIdx.x;
    int colbase = blockIdx.x * 64;
    int total8 = 2 * 64 * K / 8;
    for (int c = t; c < total8; c += 256) {
        int flat = c * 8;
        int mat = flat / (64 * K);
        int rem = flat - mat * 64 * K;
        int n = rem / K, k = rem - n * K;
        const u16* srcp = (mat ? BT2 : BT1) + (size_t)(colbase + n) * K + k;
        *(uint4*)(&Bs[mat * 64 * KP + n * KP + k]) = *(const uint4*)srcp;
    }
    __syncthreads();

    int lane = t & 63, wave = t >> 6, quad = lane >> 4, l16 = lane & 15;
    int row_base = blockIdx.y * 128 + wave * 32;
    float4v zero = {0.f, 0.f, 0.f, 0.f};
    float4v acc1[2][4], acc2[2][4];
#pragma unroll
    for (int mi = 0; mi < 2; mi++)
#pragma unroll
        for (int ni = 0; ni < 4; ni++) {
            acc1[mi][ni] = zero;
            acc2[mi][ni] = zero;
        }

#pragma unroll
    for (int ks = 0; ks < K / 32; ks++) {
        int k = ks * 32 + quad * 8;
        short8 af[2] = {{0, 0, 0, 0, 0, 0, 0, 0}, {0, 0, 0, 0, 0, 0, 0, 0}};
#pragma unroll
        for (int mi = 0; mi < 2; mi++) {
            int m = row_base + mi * 16 + l16;
            if (m < M) af[mi] = *(const short8*)(A + (size_t)m * K + k);
        }
#pragma unroll
        for (int ni = 0; ni < 4; ni++) {
            short8 b1 = *(const short8*)(&Bs[(ni * 16 + l16) * KP + k]);
            short8 b2 = *(const short8*)(&Bs[64 * KP + (ni * 16 + l16) * KP + k]);
            acc1[0][ni] = __builtin_amdgcn_mfma_f32_16x16x32_bf16(
                af[0], b1, acc1[0][ni], 0, 0, 0);
            acc1[1][ni] = __builtin_amdgcn_mfma_f32_16x16x32_bf16(
                af[1], b1, acc1[1][ni], 0, 0, 0);
            acc2[0][ni] = __builtin_amdgcn_mfma_f32_16x16x32_bf16(
                af[0], b2, acc2[0][ni], 0, 0, 0);
            acc2[1][ni] = __builtin_amdgcn_mfma_f32_16x16x32_bf16(
                af[1], b2, acc2[1][ni], 0, 0, 0);
        }
    }
#pragma unroll
    for (int mi = 0; mi < 2; mi++)
#pragma unroll
        for (int r = 0; r < 4; r++) {
            int row = row_base + mi * 16 + quad * 4 + r;
            if (row >= M) continue;
#pragma unroll
            for (int ni = 0; ni < 4; ni++) {
                int col = colbase + ni * 16 + l16;
                out1_q[(size_t)row * N + col] = f2fp8_1(acc1[mi][ni][r]);
                out2_f[(size_t)row * N + col] = acc2[mi][ni][r] + bias2[col];
            }
        }
}

// -------------------- launcher --------------------

extern "C" void kernel_launch(void* const* d_in, const int* in_sizes, int n_in,
                              void* d_out, int out_size, void* d_ws, size_t ws_size,
                              hipStream_t stream) {
    const float* x   = (const float*)d_in[0];
    const int*  eidx = (const int*)d_in[1];
    const float* Wl1 = (const float*)d_in[2];
    const float* bl1 = (const float*)d_in[3];
    const float* Wr1 = (const float*)d_in[4];
    const float* Wl2 = (const float*)d_in[5];
    const float* bl2 = (const float*)d_in[6];
    const float* Wr2 = (const float*)d_in[7];

    int n_nodes = in_sizes[0] / IN_DIM;
    int n_edges = in_sizes[1] / 2;
    const int* src = eidx;
    const int* dst = eidx + n_edges;
    int nb = (n_nodes + 63) / 64;            // buckets of 64 nodes
    int nchunk = (n_edges + EPB - 1) / EPB;  // edge chunks

    char* p = (char*)d_ws;
    auto alloc = [&](size_t bytes) {
        void* q = (void*)p;
        p += (bytes + 255) & ~(size_t)255;
        return q;
    };
    int*   bcnt    = (int*)alloc((size_t)(nb + 1) * 4);
    int*   bbase   = (int*)alloc((size_t)(nb + 1) * 4);
    int*   cntmat  = (int*)alloc((size_t)nchunk * nb * 4);
    int*   offs    = (int*)alloc((size_t)(n_nodes + 1) * 4);
    float* inv_deg = (float*)alloc((size_t)n_nodes * 4);
    u32*   pairs   = (u32*)alloc((size_t)n_edges * 4);
    int*   csr     = (int*)alloc((size_t)n_edges * 4);
    u16*   xb      = (u16*)alloc((size_t)n_nodes * IN_DIM * 2);
    u32*   xq      = (u32*)alloc((size_t)n_nodes * IN_DIM);      // fp8
    u16*   mean1b  = (u16*)alloc((size_t)n_nodes * IN_DIM * 2);
    u16*   hb      = (u16*)alloc((size_t)n_nodes * HID_DIM * 2);
    u8*    pbq     = (u8*)alloc((size_t)n_nodes * OUT_DIM);      // fp8
    u16*   WTl1b   = (u16*)alloc((size_t)IN_DIM * HID_DIM * 2);
    u16*   WTr1b   = (u16*)alloc((size_t)IN_DIM * HID_DIM * 2);
    u16*   WTl2b   = (u16*)alloc((size_t)HID_DIM * OUT_DIM * 2);
    u16*   WTr2b   = (u16*)alloc((size_t)HID_DIM * OUT_DIM * 2);

    int n4 = n_nodes * IN_DIM / 4;
    int xblocks = (n4 + 255) / 256;
    int wblocks = (4 * 32768 + 255) / 256;

    // fused hist + casts
    hist_prep<<<nchunk + xblocks + wblocks, 256, 0, stream>>>(
        dst, n_edges, nb, nchunk, cntmat, x, xb, xq, Wl1, Wr1, Wl2, Wr2,
        WTl1b, WTr1b, WTl2b, WTr2b, n4, xblocks);

    // bucketed CSR build (no global atomics)
    colscan<<<(nb + 255) / 256, 256, 0, stream>>>(cntmat, nchunk, nb, bcnt);
    bucket_scan<<<1, 1024, 0, stream>>>(bcnt, nb, n_edges, bbase);
    partition2<<<nchunk, 256, 0, stream>>>(src, dst, n_edges, nb, bbase,
                                           cntmat, pairs);
    bucket_scatter<<<nb, 256, 0, stream>>>(pairs, bbase, n_nodes, n_edges,
                                           offs, inv_deg, csr);

    int gx = (n_nodes + 127) / 128;

    // layer 1
    agg_fp8<<<(n_nodes + 3) / 4, 256, 0, stream>>>(xq, offs, csr, inv_deg,
                                                   n_nodes, mean1b, nullptr);
    {
        dim3 g(HID_DIM / 64, gx);
        gemm_l1<<<g, 256, 0, stream>>>(mean1b, xb, WTl1b, WTr1b, bl1, hb,
                                       n_nodes);
    }

    // layer 2: pbq = fp8(hb@Wl2) ; d_out = hb@Wr2 + bl2  (one pass over hb)
    {
        dim3 g(OUT_DIM / 64, gx);
        gemm_l2<<<g, 256, 0, stream>>>(hb, WTl2b, WTr2b, bl2, pbq,
                                       (float*)d_out, n_nodes);
    }
    // d_out += mean(pbq)
    agg_fp8<<<(n_nodes + 3) / 4, 256, 0, stream>>>((const u32*)pbq, offs, csr,
                                                   inv_deg, n_nodes, nullptr,
                                                   (float*)d_out);
}

// Round 9
// 297.283 us; speedup vs baseline: 8.8754x; 1.0991x over previous
//
#include <hip/hip_runtime.h>

// ---------------------------------------------------------------------------
// GraphSAGE 2-layer, bf16 MFMA + fp8 gather features. Pipeline (9 launches):
//   hist_prep:    [grid-partitioned] per-chunk LDS hist of dst>>6 -> cntmat
//                 + xb=bf16(x), xq=fp8(x) + WT*=bf16(W^T)
//   colscan_par:  1 block/bucket: parallel load of 196 chunk-counts,
//                 in-block exclusive scan -> prefixes + bucket totals
//   bucket_scan:  exclusive scan of totals -> bucket bases
//   partition2:   LDS cursors = base+prefix, LDS-atomic scatter of packed
//                 pairs ((dst&63)<<16 | src) into bucket ranges
//   bucket_scatter: 1 wg/bucket, LDS node cursors -> offs/inv_deg/csr
//   agg_fp8:      streaming mean-agg of fp8 rows, 1 wave/node, half-wave/edge
//   gemm_l1:      hb = bf16(relu(mean1@Wl1 + xb@Wr1 + bl1))   (MFMA, bf16 A)
//   gemm_l2:      pbq = fp8(hb@Wl2);  d_out = hb@Wr2 + bl2    (dual-B MFMA)
//   agg_fp8:      d_out += mean(pbq)  [projection-first: mean commutes]
// NOTES:
//  - R4 post-mortem: LDS-accumulator agg was 20x slower. Streaming
//    wave-per-node agg is the right shape. Do not revisit.
//  - R8 post-mortem: serial colscan (782 threads total) was a 48 µs latency
//    chain -> transposed to 1 block/bucket.
//  - fp8 only on aggregated operands; GEMM A/B stay bf16.
// ---------------------------------------------------------------------------

#define IN_DIM 128
#define HID_DIM 256
#define OUT_DIM 128

#define EPB 8192   // edges per chunk
#define NBMAX 784  // max buckets (50000/64 -> 782)

typedef unsigned short u16;
typedef unsigned int u32;
typedef unsigned char u8;
typedef __attribute__((ext_vector_type(8))) short short8;   // 8 bf16 (4 VGPRs)
typedef __attribute__((ext_vector_type(4))) float float4v;  // 4 fp32 acc
typedef __attribute__((ext_vector_type(2))) float float2v;

#if defined(__has_builtin)
#if __has_builtin(__builtin_amdgcn_cvt_pk_f32_fp8) && \
    __has_builtin(__builtin_amdgcn_cvt_pk_fp8_f32)
#define HAVE_HW_FP8 1
#endif
#endif

static __device__ __forceinline__ u16 f2bf(float f) {
    u32 u = __builtin_bit_cast(u32, f);
    u = (u + 0x7fffu + ((u >> 16) & 1u)) >> 16;
    return (u16)u;
}
static __device__ __forceinline__ float bf2f(u32 lo16) {
    return __builtin_bit_cast(float, lo16 << 16);
}

#if !defined(HAVE_HW_FP8)
// manual OCP e4m3 decode (handles denormals; NaN not expected in data)
static __device__ __forceinline__ float fp8_dec1(u32 v) {
    u32 s = (v & 0x80u) << 24;
    u32 e = (v >> 3) & 0xFu;
    u32 m = v & 7u;
    float mag = e ? __builtin_bit_cast(float, ((e + 120u) << 23) | (m << 20))
                  : (float)m * 0x1p-9f;
    return __builtin_bit_cast(float, __builtin_bit_cast(u32, mag) | s);
}
// manual OCP e4m3 encode, RNE, saturate to +-448
static __device__ __forceinline__ u32 fp8_enc1(float f) {
    u32 u = __builtin_bit_cast(u32, f);
    u32 s = (u >> 24) & 0x80u;
    float af = fabsf(f);
    if (af > 448.f) af = 448.f;
    u32 a = __builtin_bit_cast(u32, af);
    int e = (int)((a >> 23) & 0xFF) - 127;
    u32 q;
    if (af < 0x1p-10f) q = 0;
    else if (e < -6) {
        q = (u32)__builtin_rintf(af * 512.f);
    } else {
        u32 m = a & 0x7FFFFFu;
        u32 r = m >> 20;
        u32 rem = m & 0xFFFFFu;
        if (rem > 0x80000u || (rem == 0x80000u && (r & 1u))) r++;
        u32 ee = (u32)(e + 7);
        if (r == 8u) { r = 0; ee++; }
        if (ee >= 16u) { ee = 15u; r = 6u; }
        q = (ee << 3) | r;
    }
    return s | q;
}
#endif

// decode 2 fp8 (low or high 16 bits of dword) -> 2 f32.  HI is an immediate.
template <bool HI>
static __device__ __forceinline__ float2v fp8pk2f(u32 w) {
#if defined(HAVE_HW_FP8)
    return __builtin_amdgcn_cvt_pk_f32_fp8(w, HI);
#else
    float2v r;
    u32 b0 = HI ? ((w >> 16) & 0xFFu) : (w & 0xFFu);
    u32 b1 = HI ? (w >> 24) : ((w >> 8) & 0xFFu);
    r.x = fp8_dec1(b0);
    r.y = fp8_dec1(b1);
    return r;
#endif
}
// pack 2 f32 -> 2 fp8 into selected 16-bit word of old.  HI is an immediate.
template <bool HI>
static __device__ __forceinline__ u32 f2fp8pk(float a, float b, u32 old) {
#if defined(HAVE_HW_FP8)
    return (u32)__builtin_amdgcn_cvt_pk_fp8_f32(a, b, (int)old, HI);
#else
    u32 pk = fp8_enc1(a) | (fp8_enc1(b) << 8);
    return HI ? ((old & 0x0000FFFFu) | (pk << 16))
              : ((old & 0xFFFF0000u) | pk);
#endif
}
static __device__ __forceinline__ u8 f2fp8_1(float v) {
    return (u8)(f2fp8pk<false>(v, v, 0u) & 0xFFu);
}

// -------------------- fused hist + casts (grid-partitioned) ---------------

__global__ __launch_bounds__(256) void hist_prep(
    const int* __restrict__ dst, int n_edges, int nb, int nchunk,
    int* __restrict__ cntmat,
    const float* __restrict__ x, u16* __restrict__ xb, u32* __restrict__ xq,
    const float* __restrict__ Wl1, const float* __restrict__ Wr1,
    const float* __restrict__ Wl2, const float* __restrict__ Wr2,
    u16* __restrict__ WTl1, u16* __restrict__ WTr1,
    u16* __restrict__ WTl2, u16* __restrict__ WTr2, int n4, int xblocks) {
    __shared__ int h[NBMAX];
    int b = blockIdx.x;
    int t = threadIdx.x;
    if (b < nchunk) {
        for (int i = t; i < nb; i += 256) h[i] = 0;
        __syncthreads();
        int base = b * EPB;
        int end = min(base + EPB, n_edges);
        for (int i = base + t; i < end; i += 256) atomicAdd(&h[dst[i] >> 6], 1);
        __syncthreads();
        int* row = cntmat + (size_t)b * nb;
        for (int i = t; i < nb; i += 256) row[i] = h[i];
        return;
    }
    if (b < nchunk + xblocks) {
        int i = (b - nchunk) * 256 + t;
        if (i < n4) {
            float4 v = *(const float4*)(x + (size_t)i * 4);
            uint2 o;
            o.x = (u32)f2bf(v.x) | ((u32)f2bf(v.y) << 16);
            o.y = (u32)f2bf(v.z) | ((u32)f2bf(v.w) << 16);
            *(uint2*)(xb + (size_t)i * 4) = o;
            u32 q = f2fp8pk<false>(v.x, v.y, 0u);
            q = f2fp8pk<true>(v.z, v.w, q);
            xq[i] = q;
        }
        return;
    }
    int j = (b - nchunk - xblocks) * 256 + t;
    if (j >= 4 * 32768) return;
    int seg = j >> 15;
    int r = j & 32767;
    // seg 0/1: W [128][256] -> WT [256][128]; seg 2/3: W [256][128] -> WT [128][256]
    if (seg == 0) WTl1[r] = f2bf(Wl1[(size_t)(r & 127) * 256 + (r >> 7)]);
    else if (seg == 1) WTr1[r] = f2bf(Wr1[(size_t)(r & 127) * 256 + (r >> 7)]);
    else if (seg == 2) WTl2[r] = f2bf(Wl2[(size_t)(r & 255) * 128 + (r >> 8)]);
    else WTr2[r] = f2bf(Wr2[(size_t)(r & 255) * 128 + (r >> 8)]);
}

// -------------------- deterministic bucketed partition --------------------

// 1 block per bucket: parallel column load + in-block exclusive scan.
// (R8: serial per-thread walk was a 48 µs latency chain at 0.13% occupancy.)
__global__ __launch_bounds__(256) void colscan_par(int* __restrict__ cntmat,
                                                   int nblk, int nb,
                                                   int* __restrict__ bcnt) {
    __shared__ int s[256];
    int b = blockIdx.x;
    int t = threadIdx.x;
    int v = (t < nblk) ? cntmat[(size_t)t * nb + b] : 0;
    s[t] = v;
    __syncthreads();
    for (int off = 1; off < 256; off <<= 1) {
        int add = (t >= off) ? s[t - off] : 0;
        __syncthreads();
        s[t] += add;
        __syncthreads();
    }
    if (t < nblk) cntmat[(size_t)t * nb + b] = s[t] - v;  // exclusive prefix
    if (t == 255) bcnt[b] = s[255];                       // bucket total
}

__global__ __launch_bounds__(1024) void bucket_scan(
    const int* __restrict__ bcnt, int nb, int n_edges,
    int* __restrict__ bbase) {
    __shared__ int s[1024];
    int t = threadIdx.x;
    int v = (t < nb) ? bcnt[t] : 0;
    s[t] = v;
    __syncthreads();
    for (int off = 1; off < 1024; off <<= 1) {
        int add = (t >= off) ? s[t - off] : 0;
        __syncthreads();
        s[t] += add;
        __syncthreads();
    }
    if (t < nb) bbase[t] = s[t] - v;
    if (t == 0) bbase[nb] = n_edges;
}

__global__ __launch_bounds__(256) void partition2(
    const int* __restrict__ src, const int* __restrict__ dst, int n_edges,
    int nb, const int* __restrict__ bbase, const int* __restrict__ cntmat,
    u32* __restrict__ pairs) {
    __shared__ int cur[NBMAX];
    int t = threadIdx.x;
    const int* row = cntmat + (size_t)blockIdx.x * nb;
    for (int i = t; i < nb; i += 256) cur[i] = bbase[i] + row[i];
    __syncthreads();
    int base = blockIdx.x * EPB;
    int end = min(base + EPB, n_edges);
    for (int i = base + t; i < end; i += 256) {
        int d = dst[i];
        int pos = atomicAdd(&cur[d >> 6], 1);  // LDS atomic
        pairs[pos] = ((u32)(d & 63) << 16) | (u32)src[i];
    }
}

__global__ __launch_bounds__(256) void bucket_scatter(
    const u32* __restrict__ pairs, const int* __restrict__ bbase,
    int n_nodes, int n_edges,
    int* __restrict__ offs, float* __restrict__ inv_deg,
    int* __restrict__ csr) {
    int b = blockIdx.x;
    int t = threadIdx.x;
    int beg = bbase[b], end = bbase[b + 1];
    __shared__ int cnt[64];
    __shared__ int cur[64];
    if (t < 64) cnt[t] = 0;
    __syncthreads();
    for (int i = beg + t; i < end; i += 256)
        atomicAdd(&cnt[(pairs[i] >> 16) & 63], 1);
    __syncthreads();
    if (t < 64) {  // wave 0: shuffle exclusive scan over 64 node counts
        int v = cnt[t];
        int incl = v;
#pragma unroll
        for (int off = 1; off < 64; off <<= 1) {
            int u = __shfl_up(incl, off, 64);
            if (t >= off) incl += u;
        }
        int o = beg + incl - v;
        int node = b * 64 + t;
        if (node < n_nodes) {
            offs[node] = o;
            inv_deg[node] = 1.0f / (float)(v > 0 ? v : 1);
        }
        cur[t] = o;
    }
    if (b == 0 && t == 0) offs[n_nodes] = n_edges;
    __syncthreads();
    for (int i = beg + t; i < end; i += 256) {
        u32 pr = pairs[i];
        int p = atomicAdd(&cur[(pr >> 16) & 63], 1);
        csr[p] = (int)(pr & 0xffffu);
    }
}

// -------------------- fp8 mean aggregation (1 wave/node) ------------------
// feat: fp8 rows, 32 dwords (=128 dims) per row. Half-wave per edge:
// lanes 0-31 edge i, lanes 32-63 edge i+1; lane covers dims l32*4..+3.
// out_bf != 0: write bf16 mean.  else: out_f[row] += mean (in-place fp32).

__global__ __launch_bounds__(256) void agg_fp8(
    const u32* __restrict__ feat, const int* __restrict__ offs,
    const int* __restrict__ csr, const float* __restrict__ inv_deg,
    int n_nodes, u16* __restrict__ out_bf, float* __restrict__ out_f) {
    int wave = threadIdx.x >> 6;
    int lane = threadIdx.x & 63;
    int node = blockIdx.x * 4 + wave;
    if (node >= n_nodes) return;
    int beg = offs[node], end = offs[node + 1];
    int half = lane >> 5, l32 = lane & 31;
    float a0 = 0.f, a1 = 0.f, a2 = 0.f, a3 = 0.f;
    int i = beg;
    for (; i + 8 <= end; i += 8) {  // 8 edges: 4 slots x 2 halves
        u32 w[4];
#pragma unroll
        for (int j = 0; j < 4; j++) {
            int s = csr[i + 2 * j + half];
            w[j] = feat[(size_t)s * 32 + l32];
        }
#pragma unroll
        for (int j = 0; j < 4; j++) {
            float2v lo = fp8pk2f<false>(w[j]);
            float2v hi = fp8pk2f<true>(w[j]);
            a0 += lo.x;
            a1 += lo.y;
            a2 += hi.x;
            a3 += hi.y;
        }
    }
    for (; i < end; i += 2) {  // tail: up to 2 edges per step
        bool on = (i + half) < end;
        u32 w = 0;
        if (on) {
            int s = csr[i + half];
            w = feat[(size_t)s * 32 + l32];
        }
        float2v lo = fp8pk2f<false>(w);
        float2v hi = fp8pk2f<true>(w);
        if (on) {
            a0 += lo.x;
            a1 += lo.y;
            a2 += hi.x;
            a3 += hi.y;
        }
    }
    // combine the two halves
    a0 += __shfl_xor(a0, 32);
    a1 += __shfl_xor(a1, 32);
    a2 += __shfl_xor(a2, 32);
    a3 += __shfl_xor(a3, 32);
    float inv = inv_deg[node];
    a0 *= inv;
    a1 *= inv;
    a2 *= inv;
    a3 *= inv;
    if (half == 0) {
        if (out_bf) {
            uint2 o;
            o.x = (u32)f2bf(a0) | ((u32)f2bf(a1) << 16);
            o.y = (u32)f2bf(a2) | ((u32)f2bf(a3) << 16);
            *(uint2*)(out_bf + (size_t)node * 128 + l32 * 4) = o;
        } else {
            float4* q = (float4*)(out_f + (size_t)node * 128 + l32 * 4);
            float4 o = *q;
            o.x += a0;
            o.y += a1;
            o.z += a2;
            o.w += a3;
            *q = o;
        }
    }
}

// -------------------- MFMA GEMMs --------------------
// Frag layouts (verified m89/m91): A[m=lane&15][k=quad*8+j] from row-major,
// B-frags from B^T rows, C/D: col=lane&15, row=quad*4+reg.
// Grid: (colstrip, rowblock) so same-row col-strips are dispatch-adjacent
// and A re-reads hit L2. Block: 4 waves; tile 128(M) x 64(N).

// layer 1: hb = bf16(relu(mean1@Wl1 + xb@Wr1 + bl1)), K=128, N=256
__global__ __launch_bounds__(256) void gemm_l1(
    const u16* __restrict__ A1, const u16* __restrict__ A2,
    const u16* __restrict__ BT1, const u16* __restrict__ BT2,
    const float* __restrict__ bias, u16* __restrict__ out_bf, int M) {
    const int K = IN_DIM, N = HID_DIM, KP = K + 8;
    __shared__ u16 Bs[2 * 64 * (IN_DIM + 8)];
    int t = threadIdx.x;
    int colbase = blockIdx.x * 64;
    int total8 = 2 * 64 * K / 8;
    for (int c = t; c < total8; c += 256) {
        int flat = c * 8;
        int mat = flat / (64 * K);
        int rem = flat - mat * 64 * K;
        int n = rem / K, k = rem - n * K;
        const u16* srcp = (mat ? BT2 : BT1) + (size_t)(colbase + n) * K + k;
        *(uint4*)(&Bs[mat * 64 * KP + n * KP + k]) = *(const uint4*)srcp;
    }
    __syncthreads();

    int lane = t & 63, wave = t >> 6, quad = lane >> 4, l16 = lane & 15;
    int row_base = blockIdx.y * 128 + wave * 32;
    float4v zero = {0.f, 0.f, 0.f, 0.f};
    float4v acc[2][4];
#pragma unroll
    for (int mi = 0; mi < 2; mi++)
#pragma unroll
        for (int ni = 0; ni < 4; ni++) acc[mi][ni] = zero;

    for (int mat = 0; mat < 2; mat++) {
        const u16* A = mat ? A2 : A1;
        const u16* Bp = &Bs[mat * 64 * KP];
#pragma unroll
        for (int ks = 0; ks < K / 32; ks++) {
            int k = ks * 32 + quad * 8;
            short8 af[2] = {{0, 0, 0, 0, 0, 0, 0, 0}, {0, 0, 0, 0, 0, 0, 0, 0}};
#pragma unroll
            for (int mi = 0; mi < 2; mi++) {
                int m = row_base + mi * 16 + l16;
                if (m < M) af[mi] = *(const short8*)(A + (size_t)m * K + k);
            }
#pragma unroll
            for (int ni = 0; ni < 4; ni++) {
                short8 bfr = *(const short8*)(Bp + (ni * 16 + l16) * KP + k);
                acc[0][ni] = __builtin_amdgcn_mfma_f32_16x16x32_bf16(
                    af[0], bfr, acc[0][ni], 0, 0, 0);
                acc[1][ni] = __builtin_amdgcn_mfma_f32_16x16x32_bf16(
                    af[1], bfr, acc[1][ni], 0, 0, 0);
            }
        }
    }
#pragma unroll
    for (int mi = 0; mi < 2; mi++)
#pragma unroll
        for (int r = 0; r < 4; r++) {
            int row = row_base + mi * 16 + quad * 4 + r;
            if (row >= M) continue;
#pragma unroll
            for (int ni = 0; ni < 4; ni++) {
                int col = colbase + ni * 16 + l16;
                float v = acc[mi][ni][r] + bias[col];
                v = fmaxf(v, 0.f);
                out_bf[(size_t)row * N + col] = f2bf(v);
            }
        }
}

// layer 2 dual-B: pbq = fp8(hb@Wl2); out = hb@Wr2 + bl2 (fp32). K=256, N=128
__global__ __launch_bounds__(256) void gemm_l2(
    const u16* __restrict__ A, const u16* __restrict__ BT1,
    const u16* __restrict__ BT2, const float* __restrict__ bias2,
    u8* __restrict__ out1_q, float* __restrict__ out2_f, int M) {
    const int K = HID_DIM, N = OUT_DIM, KP = K + 8;
    __shared__ u16 Bs[2 * 64 * (HID_DIM + 8)];
    int t = threadIdx.x;
    int colbase = blockIdx.x * 64;
    int total8 = 2 * 64 * K / 8;
    for (int c = t; c < total8; c += 256) {
        int flat = c * 8;
        int mat = flat / (64 * K);
        int rem = flat - mat * 64 * K;
        int n = rem / K, k = rem - n * K;
        const u16* srcp = (mat ? BT2 : BT1) + (size_t)(colbase + n) * K + k;
        *(uint4*)(&Bs[mat * 64 * KP + n * KP + k]) = *(const uint4*)srcp;
    }
    __syncthreads();

    int lane = t & 63, wave = t >> 6, quad = lane >> 4, l16 = lane & 15;
    int row_base = blockIdx.y * 128 + wave * 32;
    float4v zero = {0.f, 0.f, 0.f, 0.f};
    float4v acc1[2][4], acc2[2][4];
#pragma unroll
    for (int mi = 0; mi < 2; mi++)
#pragma unroll
        for (int ni = 0; ni < 4; ni++) {
            acc1[mi][ni] = zero;
            acc2[mi][ni] = zero;
        }

#pragma unroll
    for (int ks = 0; ks < K / 32; ks++) {
        int k = ks * 32 + quad * 8;
        short8 af[2] = {{0, 0, 0, 0, 0, 0, 0, 0}, {0, 0, 0, 0, 0, 0, 0, 0}};
#pragma unroll
        for (int mi = 0; mi < 2; mi++) {
            int m = row_base + mi * 16 + l16;
            if (m < M) af[mi] = *(const short8*)(A + (size_t)m * K + k);
        }
#pragma unroll
        for (int ni = 0; ni < 4; ni++) {
            short8 b1 = *(const short8*)(&Bs[(ni * 16 + l16) * KP + k]);
            short8 b2 = *(const short8*)(&Bs[64 * KP + (ni * 16 + l16) * KP + k]);
            acc1[0][ni] = __builtin_amdgcn_mfma_f32_16x16x32_bf16(
                af[0], b1, acc1[0][ni], 0, 0, 0);
            acc1[1][ni] = __builtin_amdgcn_mfma_f32_16x16x32_bf16(
                af[1], b1, acc1[1][ni], 0, 0, 0);
            acc2[0][ni] = __builtin_amdgcn_mfma_f32_16x16x32_bf16(
                af[0], b2, acc2[0][ni], 0, 0, 0);
            acc2[1][ni] = __builtin_amdgcn_mfma_f32_16x16x32_bf16(
                af[1], b2, acc2[1][ni], 0, 0, 0);
        }
    }
#pragma unroll
    for (int mi = 0; mi < 2; mi++)
#pragma unroll
        for (int r = 0; r < 4; r++) {
            int row = row_base + mi * 16 + quad * 4 + r;
            if (row >= M) continue;
#pragma unroll
            for (int ni = 0; ni < 4; ni++) {
                int col = colbase + ni * 16 + l16;
                out1_q[(size_t)row * N + col] = f2fp8_1(acc1[mi][ni][r]);
                out2_f[(size_t)row * N + col] = acc2[mi][ni][r] + bias2[col];
            }
        }
}

// -------------------- launcher --------------------

extern "C" void kernel_launch(void* const* d_in, const int* in_sizes, int n_in,
                              void* d_out, int out_size, void* d_ws, size_t ws_size,
                              hipStream_t stream) {
    const float* x   = (const float*)d_in[0];
    const int*  eidx = (const int*)d_in[1];
    const float* Wl1 = (const float*)d_in[2];
    const float* bl1 = (const float*)d_in[3];
    const float* Wr1 = (const float*)d_in[4];
    const float* Wl2 = (const float*)d_in[5];
    const float* bl2 = (const float*)d_in[6];
    const float* Wr2 = (const float*)d_in[7];

    int n_nodes = in_sizes[0] / IN_DIM;
    int n_edges = in_sizes[1] / 2;
    const int* src = eidx;
    const int* dst = eidx + n_edges;
    int nb = (n_nodes + 63) / 64;            // buckets of 64 nodes
    int nchunk = (n_edges + EPB - 1) / EPB;  // edge chunks (196 <= 256)

    char* p = (char*)d_ws;
    auto alloc = [&](size_t bytes) {
        void* q = (void*)p;
        p += (bytes + 255) & ~(size_t)255;
        return q;
    };
    int*   bcnt    = (int*)alloc((size_t)(nb + 1) * 4);
    int*   bbase   = (int*)alloc((size_t)(nb + 1) * 4);
    int*   cntmat  = (int*)alloc((size_t)nchunk * nb * 4);
    int*   offs    = (int*)alloc((size_t)(n_nodes + 1) * 4);
    float* inv_deg = (float*)alloc((size_t)n_nodes * 4);
    u32*   pairs   = (u32*)alloc((size_t)n_edges * 4);
    int*   csr     = (int*)alloc((size_t)n_edges * 4);
    u16*   xb      = (u16*)alloc((size_t)n_nodes * IN_DIM * 2);
    u32*   xq      = (u32*)alloc((size_t)n_nodes * IN_DIM);      // fp8
    u16*   mean1b  = (u16*)alloc((size_t)n_nodes * IN_DIM * 2);
    u16*   hb      = (u16*)alloc((size_t)n_nodes * HID_DIM * 2);
    u8*    pbq     = (u8*)alloc((size_t)n_nodes * OUT_DIM);      // fp8
    u16*   WTl1b   = (u16*)alloc((size_t)IN_DIM * HID_DIM * 2);
    u16*   WTr1b   = (u16*)alloc((size_t)IN_DIM * HID_DIM * 2);
    u16*   WTl2b   = (u16*)alloc((size_t)HID_DIM * OUT_DIM * 2);
    u16*   WTr2b   = (u16*)alloc((size_t)HID_DIM * OUT_DIM * 2);

    int n4 = n_nodes * IN_DIM / 4;
    int xblocks = (n4 + 255) / 256;
    int wblocks = (4 * 32768 + 255) / 256;

    // fused hist + casts
    hist_prep<<<nchunk + xblocks + wblocks, 256, 0, stream>>>(
        dst, n_edges, nb, nchunk, cntmat, x, xb, xq, Wl1, Wr1, Wl2, Wr2,
        WTl1b, WTr1b, WTl2b, WTr2b, n4, xblocks);

    // bucketed CSR build (no global atomics)
    colscan_par<<<nb, 256, 0, stream>>>(cntmat, nchunk, nb, bcnt);
    bucket_scan<<<1, 1024, 0, stream>>>(bcnt, nb, n_edges, bbase);
    partition2<<<nchunk, 256, 0, stream>>>(src, dst, n_edges, nb, bbase,
                                           cntmat, pairs);
    bucket_scatter<<<nb, 256, 0, stream>>>(pairs, bbase, n_nodes, n_edges,
                                           offs, inv_deg, csr);

    int gx = (n_nodes + 127) / 128;

    // layer 1
    agg_fp8<<<(n_nodes + 3) / 4, 256, 0, stream>>>(xq, offs, csr, inv_deg,
                                                   n_nodes, mean1b, nullptr);
    {
        dim3 g(HID_DIM / 64, gx);
        gemm_l1<<<g, 256, 0, stream>>>(mean1b, xb, WTl1b, WTr1b, bl1, hb,
                                       n_nodes);
    }

    // layer 2: pbq = fp8(hb@Wl2) ; d_out = hb@Wr2 + bl2  (one pass over hb)
    {
        dim3 g(OUT_DIM / 64, gx);
        gemm_l2<<<g, 256, 0, stream>>>(hb, WTl2b, WTr2b, bl2, pbq,
                                       (float*)d_out, n_nodes);
    }
    // d_out += mean(pbq)
    agg_fp8<<<(n_nodes + 3) / 4, 256, 0, stream>>>((const u32*)pbq, offs, csr,
                                                   inv_deg, n_nodes, nullptr,
                                                   (float*)d_out);
}

// Round 10
// 280.620 us; speedup vs baseline: 9.4024x; 1.0594x over previous
//
#include <hip/hip_runtime.h>

// ---------------------------------------------------------------------------
// GraphSAGE 2-layer, bf16 MFMA + fp8 gather features. Pipeline (9 launches):
//   hist_prep:    [grid-partitioned] per-chunk LDS hist of dst>>6 -> cntmat
//                 + xb=bf16(x), xq=fp8(x) + WT*=bf16(W^T)
//   colscan_par:  1 block/bucket: parallel chunk-count scan -> prefixes+totals
//   bucket_scan:  exclusive scan of totals -> bucket bases
//   partition2:   LDS cursors, LDS-atomic scatter of packed pairs
//   bucket_scatter: 1 wg/bucket, LDS node cursors -> offs/inv_deg/csr
//   agg_fp8:      streaming mean-agg, 1 wave/node, half-wave/edge, unroll 8
//   gemm_l1:      hb = bf16(relu(mean1@Wl1 + xb@Wr1 + bl1))   (MFMA)
//   gemm_l2:      pbq = fp8(hb@Wl2);  d_out = hb@Wr2 + bl2    (dual-B MFMA)
//   agg_fp8:      d_out += mean(pbq)  [projection-first]
// NOTES:
//  - R4: LDS-accumulator agg 20x slower. Do not revisit.
//  - R8: serial colscan = 48 µs latency chain -> 1 block/bucket.
//  - R9: agg was MLP-bound (4 outstanding gathers) -> unroll 8.
//    GEMMs rebuilt: 128-col strips, B panels LDS-resident at exactly 64 KB
//    with rotation swizzle (elem' = (e + row*8) & 127) instead of +8 pad —
//    conflict-free frag reads, A re-reads cut 4x->2x (l1) / 2x->1x (l2).
// ---------------------------------------------------------------------------

#define IN_DIM 128
#define HID_DIM 256
#define OUT_DIM 128

#define EPB 8192   // edges per chunk
#define NBMAX 784  // max buckets (50000/64 -> 782)

typedef unsigned short u16;
typedef unsigned int u32;
typedef unsigned char u8;
typedef __attribute__((ext_vector_type(8))) short short8;   // 8 bf16 (4 VGPRs)
typedef __attribute__((ext_vector_type(4))) float float4v;  // 4 fp32 acc
typedef __attribute__((ext_vector_type(2))) float float2v;

#if defined(__has_builtin)
#if __has_builtin(__builtin_amdgcn_cvt_pk_f32_fp8) && \
    __has_builtin(__builtin_amdgcn_cvt_pk_fp8_f32)
#define HAVE_HW_FP8 1
#endif
#endif

static __device__ __forceinline__ u16 f2bf(float f) {
    u32 u = __builtin_bit_cast(u32, f);
    u = (u + 0x7fffu + ((u >> 16) & 1u)) >> 16;
    return (u16)u;
}
static __device__ __forceinline__ float bf2f(u32 lo16) {
    return __builtin_bit_cast(float, lo16 << 16);
}

#if !defined(HAVE_HW_FP8)
// manual OCP e4m3 decode (handles denormals; NaN not expected in data)
static __device__ __forceinline__ float fp8_dec1(u32 v) {
    u32 s = (v & 0x80u) << 24;
    u32 e = (v >> 3) & 0xFu;
    u32 m = v & 7u;
    float mag = e ? __builtin_bit_cast(float, ((e + 120u) << 23) | (m << 20))
                  : (float)m * 0x1p-9f;
    return __builtin_bit_cast(float, __builtin_bit_cast(u32, mag) | s);
}
// manual OCP e4m3 encode, RNE, saturate to +-448
static __device__ __forceinline__ u32 fp8_enc1(float f) {
    u32 u = __builtin_bit_cast(u32, f);
    u32 s = (u >> 24) & 0x80u;
    float af = fabsf(f);
    if (af > 448.f) af = 448.f;
    u32 a = __builtin_bit_cast(u32, af);
    int e = (int)((a >> 23) & 0xFF) - 127;
    u32 q;
    if (af < 0x1p-10f) q = 0;
    else if (e < -6) {
        q = (u32)__builtin_rintf(af * 512.f);
    } else {
        u32 m = a & 0x7FFFFFu;
        u32 r = m >> 20;
        u32 rem = m & 0xFFFFFu;
        if (rem > 0x80000u || (rem == 0x80000u && (r & 1u))) r++;
        u32 ee = (u32)(e + 7);
        if (r == 8u) { r = 0; ee++; }
        if (ee >= 16u) { ee = 15u; r = 6u; }
        q = (ee << 3) | r;
    }
    return s | q;
}
#endif

// decode 2 fp8 (low or high 16 bits of dword) -> 2 f32.  HI is an immediate.
template <bool HI>
static __device__ __forceinline__ float2v fp8pk2f(u32 w) {
#if defined(HAVE_HW_FP8)
    return __builtin_amdgcn_cvt_pk_f32_fp8(w, HI);
#else
    float2v r;
    u32 b0 = HI ? ((w >> 16) & 0xFFu) : (w & 0xFFu);
    u32 b1 = HI ? (w >> 24) : ((w >> 8) & 0xFFu);
    r.x = fp8_dec1(b0);
    r.y = fp8_dec1(b1);
    return r;
#endif
}
// pack 2 f32 -> 2 fp8 into selected 16-bit word of old.  HI is an immediate.
template <bool HI>
static __device__ __forceinline__ u32 f2fp8pk(float a, float b, u32 old) {
#if defined(HAVE_HW_FP8)
    return (u32)__builtin_amdgcn_cvt_pk_fp8_f32(a, b, (int)old, HI);
#else
    u32 pk = fp8_enc1(a) | (fp8_enc1(b) << 8);
    return HI ? ((old & 0x0000FFFFu) | (pk << 16))
              : ((old & 0xFFFF0000u) | pk);
#endif
}
static __device__ __forceinline__ u8 f2fp8_1(float v) {
    return (u8)(f2fp8pk<false>(v, v, 0u) & 0xFFu);
}

// -------------------- fused hist + casts (grid-partitioned) ---------------

__global__ __launch_bounds__(256) void hist_prep(
    const int* __restrict__ dst, int n_edges, int nb, int nchunk,
    int* __restrict__ cntmat,
    const float* __restrict__ x, u16* __restrict__ xb, u32* __restrict__ xq,
    const float* __restrict__ Wl1, const float* __restrict__ Wr1,
    const float* __restrict__ Wl2, const float* __restrict__ Wr2,
    u16* __restrict__ WTl1, u16* __restrict__ WTr1,
    u16* __restrict__ WTl2, u16* __restrict__ WTr2, int n4, int xblocks) {
    __shared__ int h[NBMAX];
    int b = blockIdx.x;
    int t = threadIdx.x;
    if (b < nchunk) {
        for (int i = t; i < nb; i += 256) h[i] = 0;
        __syncthreads();
        int base = b * EPB;
        int end = min(base + EPB, n_edges);
        for (int i = base + t; i < end; i += 256) atomicAdd(&h[dst[i] >> 6], 1);
        __syncthreads();
        int* row = cntmat + (size_t)b * nb;
        for (int i = t; i < nb; i += 256) row[i] = h[i];
        return;
    }
    if (b < nchunk + xblocks) {
        int i = (b - nchunk) * 256 + t;
        if (i < n4) {
            float4 v = *(const float4*)(x + (size_t)i * 4);
            uint2 o;
            o.x = (u32)f2bf(v.x) | ((u32)f2bf(v.y) << 16);
            o.y = (u32)f2bf(v.z) | ((u32)f2bf(v.w) << 16);
            *(uint2*)(xb + (size_t)i * 4) = o;
            u32 q = f2fp8pk<false>(v.x, v.y, 0u);
            q = f2fp8pk<true>(v.z, v.w, q);
            xq[i] = q;
        }
        return;
    }
    int j = (b - nchunk - xblocks) * 256 + t;
    if (j >= 4 * 32768) return;
    int seg = j >> 15;
    int r = j & 32767;
    // seg 0/1: W [128][256] -> WT [256][128]; seg 2/3: W [256][128] -> WT [128][256]
    if (seg == 0) WTl1[r] = f2bf(Wl1[(size_t)(r & 127) * 256 + (r >> 7)]);
    else if (seg == 1) WTr1[r] = f2bf(Wr1[(size_t)(r & 127) * 256 + (r >> 7)]);
    else if (seg == 2) WTl2[r] = f2bf(Wl2[(size_t)(r & 255) * 128 + (r >> 8)]);
    else WTr2[r] = f2bf(Wr2[(size_t)(r & 255) * 128 + (r >> 8)]);
}

// -------------------- deterministic bucketed partition --------------------

// 1 block per bucket: parallel column load + in-block exclusive scan.
__global__ __launch_bounds__(256) void colscan_par(int* __restrict__ cntmat,
                                                   int nblk, int nb,
                                                   int* __restrict__ bcnt) {
    __shared__ int s[256];
    int b = blockIdx.x;
    int t = threadIdx.x;
    int v = (t < nblk) ? cntmat[(size_t)t * nb + b] : 0;
    s[t] = v;
    __syncthreads();
    for (int off = 1; off < 256; off <<= 1) {
        int add = (t >= off) ? s[t - off] : 0;
        __syncthreads();
        s[t] += add;
        __syncthreads();
    }
    if (t < nblk) cntmat[(size_t)t * nb + b] = s[t] - v;  // exclusive prefix
    if (t == 255) bcnt[b] = s[255];                       // bucket total
}

__global__ __launch_bounds__(1024) void bucket_scan(
    const int* __restrict__ bcnt, int nb, int n_edges,
    int* __restrict__ bbase) {
    __shared__ int s[1024];
    int t = threadIdx.x;
    int v = (t < nb) ? bcnt[t] : 0;
    s[t] = v;
    __syncthreads();
    for (int off = 1; off < 1024; off <<= 1) {
        int add = (t >= off) ? s[t - off] : 0;
        __syncthreads();
        s[t] += add;
        __syncthreads();
    }
    if (t < nb) bbase[t] = s[t] - v;
    if (t == 0) bbase[nb] = n_edges;
}

__global__ __launch_bounds__(256) void partition2(
    const int* __restrict__ src, const int* __restrict__ dst, int n_edges,
    int nb, const int* __restrict__ bbase, const int* __restrict__ cntmat,
    u32* __restrict__ pairs) {
    __shared__ int cur[NBMAX];
    int t = threadIdx.x;
    const int* row = cntmat + (size_t)blockIdx.x * nb;
    for (int i = t; i < nb; i += 256) cur[i] = bbase[i] + row[i];
    __syncthreads();
    int base = blockIdx.x * EPB;
    int end = min(base + EPB, n_edges);
    for (int i = base + t; i < end; i += 256) {
        int d = dst[i];
        int pos = atomicAdd(&cur[d >> 6], 1);  // LDS atomic
        pairs[pos] = ((u32)(d & 63) << 16) | (u32)src[i];
    }
}

__global__ __launch_bounds__(256) void bucket_scatter(
    const u32* __restrict__ pairs, const int* __restrict__ bbase,
    int n_nodes, int n_edges,
    int* __restrict__ offs, float* __restrict__ inv_deg,
    int* __restrict__ csr) {
    int b = blockIdx.x;
    int t = threadIdx.x;
    int beg = bbase[b], end = bbase[b + 1];
    __shared__ int cnt[64];
    __shared__ int cur[64];
    if (t < 64) cnt[t] = 0;
    __syncthreads();
    for (int i = beg + t; i < end; i += 256)
        atomicAdd(&cnt[(pairs[i] >> 16) & 63], 1);
    __syncthreads();
    if (t < 64) {  // wave 0: shuffle exclusive scan over 64 node counts
        int v = cnt[t];
        int incl = v;
#pragma unroll
        for (int off = 1; off < 64; off <<= 1) {
            int u = __shfl_up(incl, off, 64);
            if (t >= off) incl += u;
        }
        int o = beg + incl - v;
        int node = b * 64 + t;
        if (node < n_nodes) {
            offs[node] = o;
            inv_deg[node] = 1.0f / (float)(v > 0 ? v : 1);
        }
        cur[t] = o;
    }
    if (b == 0 && t == 0) offs[n_nodes] = n_edges;
    __syncthreads();
    for (int i = beg + t; i < end; i += 256) {
        u32 pr = pairs[i];
        int p = atomicAdd(&cur[(pr >> 16) & 63], 1);
        csr[p] = (int)(pr & 0xffffu);
    }
}

// -------------------- fp8 mean aggregation (1 wave/node) ------------------
// feat: fp8 rows, 32 dwords (=128 dims) per row. Half-wave per edge; unroll 8
// (16 edges / wave-iter) for memory-level parallelism.
// out_bf != 0: write bf16 mean.  else: out_f[row] += mean (in-place fp32).

__global__ __launch_bounds__(256) void agg_fp8(
    const u32* __restrict__ feat, const int* __restrict__ offs,
    const int* __restrict__ csr, const float* __restrict__ inv_deg,
    int n_nodes, u16* __restrict__ out_bf, float* __restrict__ out_f) {
    int wave = threadIdx.x >> 6;
    int lane = threadIdx.x & 63;
    int node = blockIdx.x * 4 + wave;
    if (node >= n_nodes) return;
    int beg = offs[node], end = offs[node + 1];
    int half = lane >> 5, l32 = lane & 31;
    float a0 = 0.f, a1 = 0.f, a2 = 0.f, a3 = 0.f;
    int i = beg;
    for (; i + 16 <= end; i += 16) {  // 16 edges: 8 slots x 2 halves
        u32 w[8];
#pragma unroll
        for (int j = 0; j < 8; j++) {
            int s = csr[i + 2 * j + half];
            w[j] = feat[(size_t)s * 32 + l32];
        }
#pragma unroll
        for (int j = 0; j < 8; j++) {
            float2v lo = fp8pk2f<false>(w[j]);
            float2v hi = fp8pk2f<true>(w[j]);
            a0 += lo.x;
            a1 += lo.y;
            a2 += hi.x;
            a3 += hi.y;
        }
    }
    if (i + 8 <= end) {  // 8-edge remainder
        u32 w[4];
#pragma unroll
        for (int j = 0; j < 4; j++) {
            int s = csr[i + 2 * j + half];
            w[j] = feat[(size_t)s * 32 + l32];
        }
#pragma unroll
        for (int j = 0; j < 4; j++) {
            float2v lo = fp8pk2f<false>(w[j]);
            float2v hi = fp8pk2f<true>(w[j]);
            a0 += lo.x;
            a1 += lo.y;
            a2 += hi.x;
            a3 += hi.y;
        }
        i += 8;
    }
    for (; i < end; i += 2) {  // tail: up to 2 edges per step
        bool on = (i + half) < end;
        u32 w = 0;
        if (on) {
            int s = csr[i + half];
            w = feat[(size_t)s * 32 + l32];
        }
        float2v lo = fp8pk2f<false>(w);
        float2v hi = fp8pk2f<true>(w);
        if (on) {
            a0 += lo.x;
            a1 += lo.y;
            a2 += hi.x;
            a3 += hi.y;
        }
    }
    // combine the two halves
    a0 += __shfl_xor(a0, 32);
    a1 += __shfl_xor(a1, 32);
    a2 += __shfl_xor(a2, 32);
    a3 += __shfl_xor(a3, 32);
    float inv = inv_deg[node];
    a0 *= inv;
    a1 *= inv;
    a2 *= inv;
    a3 *= inv;
    if (half == 0) {
        if (out_bf) {
            uint2 o;
            o.x = (u32)f2bf(a0) | ((u32)f2bf(a1) << 16);
            o.y = (u32)f2bf(a2) | ((u32)f2bf(a3) << 16);
            *(uint2*)(out_bf + (size_t)node * 128 + l32 * 4) = o;
        } else {
            float4* q = (float4*)(out_f + (size_t)node * 128 + l32 * 4);
            float4 o = *q;
            o.x += a0;
            o.y += a1;
            o.z += a2;
            o.w += a3;
            *q = o;
        }
    }
}

// -------------------- MFMA GEMMs --------------------
// Frag layouts (verified m89/m91): A[m=lane&15][k=quad*8+j] from row-major,
// B-frags from B^T rows, C/D: col=lane&15, row=quad*4+reg.
// 128-col strips; B^T panels LDS-resident at exactly 64 KB with rotation
// swizzle: element e of row n stored at (e + n*8) & 127 — rows shift 4
// dwords, frag-read lanes spread over all 32 banks (2-way residual = free).
// Block: 4 waves; wave = 32(M) x 128(N) via 2x8 of 16x16x32 mfma.

// layer 1: hb = bf16(relu(mean1@Wl1 + xb@Wr1 + bl1)), K=128, N=256
__global__ __launch_bounds__(256) void gemm_l1(
    const u16* __restrict__ A1, const u16* __restrict__ A2,
    const u16* __restrict__ BT1, const u16* __restrict__ BT2,
    const float* __restrict__ bias, u16* __restrict__ out_bf, int M) {
    const int K = IN_DIM, N = HID_DIM;
    __shared__ u16 Bs[2][128 * 128];  // 64 KB
    int t = threadIdx.x;
    int colbase = blockIdx.x * 128;

#pragma unroll
    for (int mat = 0; mat < 2; mat++) {
        const u16* BT = mat ? BT2 : BT1;
        for (int c = t; c < 2048; c += 256) {
            int n = c >> 4;          // panel row 0..127
            int e = (c & 15) * 8;    // element 0..120
            int es = (e + n * 8) & 127;
            *(uint4*)&Bs[mat][n * 128 + es] =
                *(const uint4*)(BT + (size_t)(colbase + n) * K + e);
        }
    }
    __syncthreads();

    int lane = t & 63, wave = t >> 6, quad = lane >> 4, l16 = lane & 15;
    int row_base = blockIdx.y * 128 + wave * 32;
    float4v zero = {0.f, 0.f, 0.f, 0.f};
    float4v acc[2][8];
#pragma unroll
    for (int mi = 0; mi < 2; mi++)
#pragma unroll
        for (int ni = 0; ni < 8; ni++) acc[mi][ni] = zero;

    for (int mat = 0; mat < 2; mat++) {
        const u16* A = mat ? A2 : A1;
#pragma unroll
        for (int ks = 0; ks < 4; ks++) {
            int k = ks * 32 + quad * 8;
            short8 af[2] = {{0, 0, 0, 0, 0, 0, 0, 0}, {0, 0, 0, 0, 0, 0, 0, 0}};
#pragma unroll
            for (int mi = 0; mi < 2; mi++) {
                int m = row_base + mi * 16 + l16;
                if (m < M) af[mi] = *(const short8*)(A + (size_t)m * K + k);
            }
#pragma unroll
            for (int ni = 0; ni < 8; ni++) {
                int nn = ni * 16 + l16;
                int es = (k + nn * 8) & 127;
                short8 bfr = *(const short8*)&Bs[mat][nn * 128 + es];
                acc[0][ni] = __builtin_amdgcn_mfma_f32_16x16x32_bf16(
                    af[0], bfr, acc[0][ni], 0, 0, 0);
                acc[1][ni] = __builtin_amdgcn_mfma_f32_16x16x32_bf16(
                    af[1], bfr, acc[1][ni], 0, 0, 0);
            }
        }
    }
#pragma unroll
    for (int mi = 0; mi < 2; mi++)
#pragma unroll
        for (int r = 0; r < 4; r++) {
            int row = row_base + mi * 16 + quad * 4 + r;
            if (row >= M) continue;
#pragma unroll
            for (int ni = 0; ni < 8; ni++) {
                int col = colbase + ni * 16 + l16;
                float v = acc[mi][ni][r] + bias[col];
                v = fmaxf(v, 0.f);
                out_bf[(size_t)row * N + col] = f2bf(v);
            }
        }
}

// layer 2 dual-B: pbq = fp8(hb@Wl2); out = hb@Wr2 + bl2 (fp32). K=256, N=128
__global__ __launch_bounds__(256) void gemm_l2(
    const u16* __restrict__ A, const u16* __restrict__ BT1,
    const u16* __restrict__ BT2, const float* __restrict__ bias2,
    u8* __restrict__ out1_q, float* __restrict__ out2_f, int M) {
    const int K = HID_DIM, N = OUT_DIM;
    __shared__ u16 Bs[2][128 * 128];  // 64 KB, one 128-K chunk of each B
    int t = threadIdx.x;
    int lane = t & 63, wave = t >> 6, quad = lane >> 4, l16 = lane & 15;
    int row_base = blockIdx.y * 128 + wave * 32;
    float4v zero = {0.f, 0.f, 0.f, 0.f};
    float4v acc1[2][8], acc2[2][8];
#pragma unroll
    for (int mi = 0; mi < 2; mi++)
#pragma unroll
        for (int ni = 0; ni < 8; ni++) {
            acc1[mi][ni] = zero;
            acc2[mi][ni] = zero;
        }

    for (int kc = 0; kc < 2; kc++) {
        if (kc) __syncthreads();  // compute of previous chunk done
#pragma unroll
        for (int mat = 0; mat < 2; mat++) {
            const u16* BT = mat ? BT2 : BT1;
            for (int c = t; c < 2048; c += 256) {
                int n = c >> 4;
                int e = (c & 15) * 8;
                int es = (e + n * 8) & 127;
                *(uint4*)&Bs[mat][n * 128 + es] =
                    *(const uint4*)(BT + (size_t)n * K + kc * 128 + e);
            }
        }
        __syncthreads();
#pragma unroll
        for (int ks = 0; ks < 4; ks++) {
            int k = ks * 32 + quad * 8;
            int gk = kc * 128 + k;
            short8 af[2] = {{0, 0, 0, 0, 0, 0, 0, 0}, {0, 0, 0, 0, 0, 0, 0, 0}};
#pragma unroll
            for (int mi = 0; mi < 2; mi++) {
                int m = row_base + mi * 16 + l16;
                if (m < M) af[mi] = *(const short8*)(A + (size_t)m * K + gk);
            }
#pragma unroll
            for (int ni = 0; ni < 8; ni++) {
                int nn = ni * 16 + l16;
                int es = (k + nn * 8) & 127;
                short8 b1 = *(const short8*)&Bs[0][nn * 128 + es];
                short8 b2 = *(const short8*)&Bs[1][nn * 128 + es];
                acc1[0][ni] = __builtin_amdgcn_mfma_f32_16x16x32_bf16(
                    af[0], b1, acc1[0][ni], 0, 0, 0);
                acc1[1][ni] = __builtin_amdgcn_mfma_f32_16x16x32_bf16(
                    af[1], b1, acc1[1][ni], 0, 0, 0);
                acc2[0][ni] = __builtin_amdgcn_mfma_f32_16x16x32_bf16(
                    af[0], b2, acc2[0][ni], 0, 0, 0);
                acc2[1][ni] = __builtin_amdgcn_mfma_f32_16x16x32_bf16(
                    af[1], b2, acc2[1][ni], 0, 0, 0);
            }
        }
    }
#pragma unroll
    for (int mi = 0; mi < 2; mi++)
#pragma unroll
        for (int r = 0; r < 4; r++) {
            int row = row_base + mi * 16 + quad * 4 + r;
            if (row >= M) continue;
#pragma unroll
            for (int ni = 0; ni < 8; ni++) {
                int col = ni * 16 + l16;
                out1_q[(size_t)row * N + col] = f2fp8_1(acc1[mi][ni][r]);
                out2_f[(size_t)row * N + col] = acc2[mi][ni][r] + bias2[col];
            }
        }
}

// -------------------- launcher --------------------

extern "C" void kernel_launch(void* const* d_in, const int* in_sizes, int n_in,
                              void* d_out, int out_size, void* d_ws, size_t ws_size,
                              hipStream_t stream) {
    const float* x   = (const float*)d_in[0];
    const int*  eidx = (const int*)d_in[1];
    const float* Wl1 = (const float*)d_in[2];
    const float* bl1 = (const float*)d_in[3];
    const float* Wr1 = (const float*)d_in[4];
    const float* Wl2 = (const float*)d_in[5];
    const float* bl2 = (const float*)d_in[6];
    const float* Wr2 = (const float*)d_in[7];

    int n_nodes = in_sizes[0] / IN_DIM;
    int n_edges = in_sizes[1] / 2;
    const int* src = eidx;
    const int* dst = eidx + n_edges;
    int nb = (n_nodes + 63) / 64;            // buckets of 64 nodes
    int nchunk = (n_edges + EPB - 1) / EPB;  // edge chunks (196 <= 256)

    char* p = (char*)d_ws;
    auto alloc = [&](size_t bytes) {
        void* q = (void*)p;
        p += (bytes + 255) & ~(size_t)255;
        return q;
    };
    int*   bcnt    = (int*)alloc((size_t)(nb + 1) * 4);
    int*   bbase   = (int*)alloc((size_t)(nb + 1) * 4);
    int*   cntmat  = (int*)alloc((size_t)nchunk * nb * 4);
    int*   offs    = (int*)alloc((size_t)(n_nodes + 1) * 4);
    float* inv_deg = (float*)alloc((size_t)n_nodes * 4);
    u32*   pairs   = (u32*)alloc((size_t)n_edges * 4);
    int*   csr     = (int*)alloc((size_t)n_edges * 4);
    u16*   xb      = (u16*)alloc((size_t)n_nodes * IN_DIM * 2);
    u32*   xq      = (u32*)alloc((size_t)n_nodes * IN_DIM);      // fp8
    u16*   mean1b  = (u16*)alloc((size_t)n_nodes * IN_DIM * 2);
    u16*   hb      = (u16*)alloc((size_t)n_nodes * HID_DIM * 2);
    u8*    pbq     = (u8*)alloc((size_t)n_nodes * OUT_DIM);      // fp8
    u16*   WTl1b   = (u16*)alloc((size_t)IN_DIM * HID_DIM * 2);
    u16*   WTr1b   = (u16*)alloc((size_t)IN_DIM * HID_DIM * 2);
    u16*   WTl2b   = (u16*)alloc((size_t)HID_DIM * OUT_DIM * 2);
    u16*   WTr2b   = (u16*)alloc((size_t)HID_DIM * OUT_DIM * 2);

    int n4 = n_nodes * IN_DIM / 4;
    int xblocks = (n4 + 255) / 256;
    int wblocks = (4 * 32768 + 255) / 256;

    // fused hist + casts
    hist_prep<<<nchunk + xblocks + wblocks, 256, 0, stream>>>(
        dst, n_edges, nb, nchunk, cntmat, x, xb, xq, Wl1, Wr1, Wl2, Wr2,
        WTl1b, WTr1b, WTl2b, WTr2b, n4, xblocks);

    // bucketed CSR build (no global atomics)
    colscan_par<<<nb, 256, 0, stream>>>(cntmat, nchunk, nb, bcnt);
    bucket_scan<<<1, 1024, 0, stream>>>(bcnt, nb, n_edges, bbase);
    partition2<<<nchunk, 256, 0, stream>>>(src, dst, n_edges, nb, bbase,
                                           cntmat, pairs);
    bucket_scatter<<<nb, 256, 0, stream>>>(pairs, bbase, n_nodes, n_edges,
                                           offs, inv_deg, csr);

    int gx = (n_nodes + 127) / 128;

    // layer 1
    agg_fp8<<<(n_nodes + 3) / 4, 256, 0, stream>>>(xq, offs, csr, inv_deg,
                                                   n_nodes, mean1b, nullptr);
    {
        dim3 g(HID_DIM / 128, gx);
        gemm_l1<<<g, 256, 0, stream>>>(mean1b, xb, WTl1b, WTr1b, bl1, hb,
                                       n_nodes);
    }

    // layer 2: pbq = fp8(hb@Wl2) ; d_out = hb@Wr2 + bl2  (one pass over hb)
    {
        dim3 g(1, gx);
        gemm_l2<<<g, 256, 0, stream>>>(hb, WTl2b, WTr2b, bl2, pbq,
                                       (float*)d_out, n_nodes);
    }
    // d_out += mean(pbq)
    agg_fp8<<<(n_nodes + 3) / 4, 256, 0, stream>>>((const u32*)pbq, offs, csr,
                                                   inv_deg, n_nodes, nullptr,
                                                   (float*)d_out);
}

// Round 11
// 263.745 us; speedup vs baseline: 10.0040x; 1.0640x over previous
//
#include <hip/hip_runtime.h>

// ---------------------------------------------------------------------------
// GraphSAGE 2-layer, bf16 MFMA + fp8 gather features. Pipeline (9 launches):
//   hist_prep:    [grid-partitioned] per-chunk LDS hist of dst>>6 -> cntmat
//                 + xb=bf16(x), xq=fp8(x) + WT*=bf16(W^T)
//   colscan_par:  1 block/bucket: parallel chunk-count scan -> prefixes+totals
//   bucket_scan:  exclusive scan of totals -> bucket bases
//   partition2:   LDS cursors, LDS-atomic scatter of packed pairs
//   bucket_scatter: 1 wg/bucket, LDS node cursors -> offs/inv_deg/csr
//   agg_fp8:      streaming mean-agg, 1 wave/node, half-wave/edge, 32-edge
//                 batches (16 outstanding gathers/lane — L3-latency bound)
//   gemm_l1:      hb = bf16(relu(mean1@Wl1 + xb@Wr1 + bl1))   (MFMA)
//   gemm_l2:      pbq = fp8(hb@Wl2);  d_out = hb@Wr2 + bl2    (dual-B MFMA)
//   agg_fp8:      d_out += mean(pbq)  [projection-first]
// NOTES:
//  - R4: LDS-accumulator agg 20x slower. Do not revisit.
//  - R8: serial colscan = 48 µs latency chain -> 1 block/bucket.
//  - R9 counters: agg is L3-LATENCY bound (Little's law matches 2.5 TB/s
//    L2-miss at 8 outstanding) -> R10 doubles outstanding to 16.
//  - gemm_l1: B staged per-mat (32 KB LDS) -> 4-5 blocks/CU instead of 2;
//    staging overlaps compute across blocks. gemm_l2 keeps 64 KB (A once).
//  - LDS rotation swizzle (elem' = (e + row*8) & 127): conflict-free frag
//    reads without padding; 64/32 KB exact.
// ---------------------------------------------------------------------------

#define IN_DIM 128
#define HID_DIM 256
#define OUT_DIM 128

#define EPB 8192   // edges per chunk
#define NBMAX 784  // max buckets (50000/64 -> 782)

typedef unsigned short u16;
typedef unsigned int u32;
typedef unsigned char u8;
typedef __attribute__((ext_vector_type(8))) short short8;   // 8 bf16 (4 VGPRs)
typedef __attribute__((ext_vector_type(4))) float float4v;  // 4 fp32 acc
typedef __attribute__((ext_vector_type(2))) float float2v;

#if defined(__has_builtin)
#if __has_builtin(__builtin_amdgcn_cvt_pk_f32_fp8) && \
    __has_builtin(__builtin_amdgcn_cvt_pk_fp8_f32)
#define HAVE_HW_FP8 1
#endif
#endif

static __device__ __forceinline__ u16 f2bf(float f) {
    u32 u = __builtin_bit_cast(u32, f);
    u = (u + 0x7fffu + ((u >> 16) & 1u)) >> 16;
    return (u16)u;
}
static __device__ __forceinline__ float bf2f(u32 lo16) {
    return __builtin_bit_cast(float, lo16 << 16);
}

#if !defined(HAVE_HW_FP8)
// manual OCP e4m3 decode (handles denormals; NaN not expected in data)
static __device__ __forceinline__ float fp8_dec1(u32 v) {
    u32 s = (v & 0x80u) << 24;
    u32 e = (v >> 3) & 0xFu;
    u32 m = v & 7u;
    float mag = e ? __builtin_bit_cast(float, ((e + 120u) << 23) | (m << 20))
                  : (float)m * 0x1p-9f;
    return __builtin_bit_cast(float, __builtin_bit_cast(u32, mag) | s);
}
// manual OCP e4m3 encode, RNE, saturate to +-448
static __device__ __forceinline__ u32 fp8_enc1(float f) {
    u32 u = __builtin_bit_cast(u32, f);
    u32 s = (u >> 24) & 0x80u;
    float af = fabsf(f);
    if (af > 448.f) af = 448.f;
    u32 a = __builtin_bit_cast(u32, af);
    int e = (int)((a >> 23) & 0xFF) - 127;
    u32 q;
    if (af < 0x1p-10f) q = 0;
    else if (e < -6) {
        q = (u32)__builtin_rintf(af * 512.f);
    } else {
        u32 m = a & 0x7FFFFFu;
        u32 r = m >> 20;
        u32 rem = m & 0xFFFFFu;
        if (rem > 0x80000u || (rem == 0x80000u && (r & 1u))) r++;
        u32 ee = (u32)(e + 7);
        if (r == 8u) { r = 0; ee++; }
        if (ee >= 16u) { ee = 15u; r = 6u; }
        q = (ee << 3) | r;
    }
    return s | q;
}
#endif

// decode 2 fp8 (low or high 16 bits of dword) -> 2 f32.  HI is an immediate.
template <bool HI>
static __device__ __forceinline__ float2v fp8pk2f(u32 w) {
#if defined(HAVE_HW_FP8)
    return __builtin_amdgcn_cvt_pk_f32_fp8(w, HI);
#else
    float2v r;
    u32 b0 = HI ? ((w >> 16) & 0xFFu) : (w & 0xFFu);
    u32 b1 = HI ? (w >> 24) : ((w >> 8) & 0xFFu);
    r.x = fp8_dec1(b0);
    r.y = fp8_dec1(b1);
    return r;
#endif
}
// pack 2 f32 -> 2 fp8 into selected 16-bit word of old.  HI is an immediate.
template <bool HI>
static __device__ __forceinline__ u32 f2fp8pk(float a, float b, u32 old) {
#if defined(HAVE_HW_FP8)
    return (u32)__builtin_amdgcn_cvt_pk_fp8_f32(a, b, (int)old, HI);
#else
    u32 pk = fp8_enc1(a) | (fp8_enc1(b) << 8);
    return HI ? ((old & 0x0000FFFFu) | (pk << 16))
              : ((old & 0xFFFF0000u) | pk);
#endif
}
static __device__ __forceinline__ u8 f2fp8_1(float v) {
    return (u8)(f2fp8pk<false>(v, v, 0u) & 0xFFu);
}

// -------------------- fused hist + casts (grid-partitioned) ---------------

__global__ __launch_bounds__(256) void hist_prep(
    const int* __restrict__ dst, int n_edges, int nb, int nchunk,
    int* __restrict__ cntmat,
    const float* __restrict__ x, u16* __restrict__ xb, u32* __restrict__ xq,
    const float* __restrict__ Wl1, const float* __restrict__ Wr1,
    const float* __restrict__ Wl2, const float* __restrict__ Wr2,
    u16* __restrict__ WTl1, u16* __restrict__ WTr1,
    u16* __restrict__ WTl2, u16* __restrict__ WTr2, int n4, int xblocks) {
    __shared__ int h[NBMAX];
    int b = blockIdx.x;
    int t = threadIdx.x;
    if (b < nchunk) {
        for (int i = t; i < nb; i += 256) h[i] = 0;
        __syncthreads();
        int base = b * EPB;
        int end = min(base + EPB, n_edges);
        for (int i = base + t; i < end; i += 256) atomicAdd(&h[dst[i] >> 6], 1);
        __syncthreads();
        int* row = cntmat + (size_t)b * nb;
        for (int i = t; i < nb; i += 256) row[i] = h[i];
        return;
    }
    if (b < nchunk + xblocks) {
        int i = (b - nchunk) * 256 + t;
        if (i < n4) {
            float4 v = *(const float4*)(x + (size_t)i * 4);
            uint2 o;
            o.x = (u32)f2bf(v.x) | ((u32)f2bf(v.y) << 16);
            o.y = (u32)f2bf(v.z) | ((u32)f2bf(v.w) << 16);
            *(uint2*)(xb + (size_t)i * 4) = o;
            u32 q = f2fp8pk<false>(v.x, v.y, 0u);
            q = f2fp8pk<true>(v.z, v.w, q);
            xq[i] = q;
        }
        return;
    }
    int j = (b - nchunk - xblocks) * 256 + t;
    if (j >= 4 * 32768) return;
    int seg = j >> 15;
    int r = j & 32767;
    // seg 0/1: W [128][256] -> WT [256][128]; seg 2/3: W [256][128] -> WT [128][256]
    if (seg == 0) WTl1[r] = f2bf(Wl1[(size_t)(r & 127) * 256 + (r >> 7)]);
    else if (seg == 1) WTr1[r] = f2bf(Wr1[(size_t)(r & 127) * 256 + (r >> 7)]);
    else if (seg == 2) WTl2[r] = f2bf(Wl2[(size_t)(r & 255) * 128 + (r >> 8)]);
    else WTr2[r] = f2bf(Wr2[(size_t)(r & 255) * 128 + (r >> 8)]);
}

// -------------------- deterministic bucketed partition --------------------

// 1 block per bucket: parallel column load + in-block exclusive scan.
__global__ __launch_bounds__(256) void colscan_par(int* __restrict__ cntmat,
                                                   int nblk, int nb,
                                                   int* __restrict__ bcnt) {
    __shared__ int s[256];
    int b = blockIdx.x;
    int t = threadIdx.x;
    int v = (t < nblk) ? cntmat[(size_t)t * nb + b] : 0;
    s[t] = v;
    __syncthreads();
    for (int off = 1; off < 256; off <<= 1) {
        int add = (t >= off) ? s[t - off] : 0;
        __syncthreads();
        s[t] += add;
        __syncthreads();
    }
    if (t < nblk) cntmat[(size_t)t * nb + b] = s[t] - v;  // exclusive prefix
    if (t == 255) bcnt[b] = s[255];                       // bucket total
}

__global__ __launch_bounds__(1024) void bucket_scan(
    const int* __restrict__ bcnt, int nb, int n_edges,
    int* __restrict__ bbase) {
    __shared__ int s[1024];
    int t = threadIdx.x;
    int v = (t < nb) ? bcnt[t] : 0;
    s[t] = v;
    __syncthreads();
    for (int off = 1; off < 1024; off <<= 1) {
        int add = (t >= off) ? s[t - off] : 0;
        __syncthreads();
        s[t] += add;
        __syncthreads();
    }
    if (t < nb) bbase[t] = s[t] - v;
    if (t == 0) bbase[nb] = n_edges;
}

__global__ __launch_bounds__(256) void partition2(
    const int* __restrict__ src, const int* __restrict__ dst, int n_edges,
    int nb, const int* __restrict__ bbase, const int* __restrict__ cntmat,
    u32* __restrict__ pairs) {
    __shared__ int cur[NBMAX];
    int t = threadIdx.x;
    const int* row = cntmat + (size_t)blockIdx.x * nb;
    for (int i = t; i < nb; i += 256) cur[i] = bbase[i] + row[i];
    __syncthreads();
    int base = blockIdx.x * EPB;
    int end = min(base + EPB, n_edges);
    for (int i = base + t; i < end; i += 256) {
        int d = dst[i];
        int pos = atomicAdd(&cur[d >> 6], 1);  // LDS atomic
        pairs[pos] = ((u32)(d & 63) << 16) | (u32)src[i];
    }
}

__global__ __launch_bounds__(256) void bucket_scatter(
    const u32* __restrict__ pairs, const int* __restrict__ bbase,
    int n_nodes, int n_edges,
    int* __restrict__ offs, float* __restrict__ inv_deg,
    int* __restrict__ csr) {
    int b = blockIdx.x;
    int t = threadIdx.x;
    int beg = bbase[b], end = bbase[b + 1];
    __shared__ int cnt[64];
    __shared__ int cur[64];
    if (t < 64) cnt[t] = 0;
    __syncthreads();
    for (int i = beg + t; i < end; i += 256)
        atomicAdd(&cnt[(pairs[i] >> 16) & 63], 1);
    __syncthreads();
    if (t < 64) {  // wave 0: shuffle exclusive scan over 64 node counts
        int v = cnt[t];
        int incl = v;
#pragma unroll
        for (int off = 1; off < 64; off <<= 1) {
            int u = __shfl_up(incl, off, 64);
            if (t >= off) incl += u;
        }
        int o = beg + incl - v;
        int node = b * 64 + t;
        if (node < n_nodes) {
            offs[node] = o;
            inv_deg[node] = 1.0f / (float)(v > 0 ? v : 1);
        }
        cur[t] = o;
    }
    if (b == 0 && t == 0) offs[n_nodes] = n_edges;
    __syncthreads();
    for (int i = beg + t; i < end; i += 256) {
        u32 pr = pairs[i];
        int p = atomicAdd(&cur[(pr >> 16) & 63], 1);
        csr[p] = (int)(pr & 0xffffu);
    }
}

// -------------------- fp8 mean aggregation (1 wave/node) ------------------
// feat: fp8 rows, 32 dwords (=128 dims) per row. Half-wave per edge; 32-edge
// batches = 16 outstanding 128B gathers per lane (L3-latency bound: Little's
// law at 8 outstanding matched the observed 2.5 TB/s L2-miss rate).
// out_bf != 0: write bf16 mean.  else: out_f[row] += mean (in-place fp32).

__global__ __launch_bounds__(256) void agg_fp8(
    const u32* __restrict__ feat, const int* __restrict__ offs,
    const int* __restrict__ csr, const float* __restrict__ inv_deg,
    int n_nodes, u16* __restrict__ out_bf, float* __restrict__ out_f) {
    int wave = threadIdx.x >> 6;
    int lane = threadIdx.x & 63;
    int node = blockIdx.x * 4 + wave;
    if (node >= n_nodes) return;
    int beg = offs[node], end = offs[node + 1];
    int half = lane >> 5, l32 = lane & 31;
    float a0 = 0.f, a1 = 0.f, a2 = 0.f, a3 = 0.f;
    int i = beg;
    for (; i + 32 <= end; i += 32) {  // 32 edges: 16 slots x 2 halves
        u32 w[16];
#pragma unroll
        for (int j = 0; j < 16; j++) {
            int s = csr[i + 2 * j + half];
            w[j] = feat[(size_t)s * 32 + l32];
        }
#pragma unroll
        for (int j = 0; j < 16; j++) {
            float2v lo = fp8pk2f<false>(w[j]);
            float2v hi = fp8pk2f<true>(w[j]);
            a0 += lo.x;
            a1 += lo.y;
            a2 += hi.x;
            a3 += hi.y;
        }
    }
    if (i + 16 <= end) {  // 16-edge remainder
        u32 w[8];
#pragma unroll
        for (int j = 0; j < 8; j++) {
            int s = csr[i + 2 * j + half];
            w[j] = feat[(size_t)s * 32 + l32];
        }
#pragma unroll
        for (int j = 0; j < 8; j++) {
            float2v lo = fp8pk2f<false>(w[j]);
            float2v hi = fp8pk2f<true>(w[j]);
            a0 += lo.x;
            a1 += lo.y;
            a2 += hi.x;
            a3 += hi.y;
        }
        i += 16;
    }
    if (i + 8 <= end) {  // 8-edge remainder
        u32 w[4];
#pragma unroll
        for (int j = 0; j < 4; j++) {
            int s = csr[i + 2 * j + half];
            w[j] = feat[(size_t)s * 32 + l32];
        }
#pragma unroll
        for (int j = 0; j < 4; j++) {
            float2v lo = fp8pk2f<false>(w[j]);
            float2v hi = fp8pk2f<true>(w[j]);
            a0 += lo.x;
            a1 += lo.y;
            a2 += hi.x;
            a3 += hi.y;
        }
        i += 8;
    }
    for (; i < end; i += 2) {  // tail: up to 2 edges per step
        bool on = (i + half) < end;
        u32 w = 0;
        if (on) {
            int s = csr[i + half];
            w = feat[(size_t)s * 32 + l32];
        }
        float2v lo = fp8pk2f<false>(w);
        float2v hi = fp8pk2f<true>(w);
        if (on) {
            a0 += lo.x;
            a1 += lo.y;
            a2 += hi.x;
            a3 += hi.y;
        }
    }
    // combine the two halves
    a0 += __shfl_xor(a0, 32);
    a1 += __shfl_xor(a1, 32);
    a2 += __shfl_xor(a2, 32);
    a3 += __shfl_xor(a3, 32);
    float inv = inv_deg[node];
    a0 *= inv;
    a1 *= inv;
    a2 *= inv;
    a3 *= inv;
    if (half == 0) {
        if (out_bf) {
            uint2 o;
            o.x = (u32)f2bf(a0) | ((u32)f2bf(a1) << 16);
            o.y = (u32)f2bf(a2) | ((u32)f2bf(a3) << 16);
            *(uint2*)(out_bf + (size_t)node * 128 + l32 * 4) = o;
        } else {
            float4* q = (float4*)(out_f + (size_t)node * 128 + l32 * 4);
            float4 o = *q;
            o.x += a0;
            o.y += a1;
            o.z += a2;
            o.w += a3;
            *q = o;
        }
    }
}

// -------------------- MFMA GEMMs --------------------
// Frag layouts (verified m89/m91): A[m=lane&15][k=quad*8+j] from row-major,
// B-frags from B^T rows, C/D: col=lane&15, row=quad*4+reg.
// 128-col strips; B^T panels LDS-resident with rotation swizzle:
// element e of row n stored at (e + n*8) & 127 — conflict-free frag reads.
// Block: 4 waves; wave = 32(M) x 128(N) via 2x8 of 16x16x32 mfma.

// layer 1: hb = bf16(relu(mean1@Wl1 + xb@Wr1 + bl1)), K=128, N=256.
// B staged per-mat (32 KB LDS) -> 4-5 blocks/CU; C = A1B1 + A2B2 accumulates
// across the two stages (no extra global traffic: A1,A2 distinct arrays).
__global__ __launch_bounds__(256) void gemm_l1(
    const u16* __restrict__ A1, const u16* __restrict__ A2,
    const u16* __restrict__ BT1, const u16* __restrict__ BT2,
    const float* __restrict__ bias, u16* __restrict__ out_bf, int M) {
    const int K = IN_DIM, N = HID_DIM;
    __shared__ u16 Bs[128 * 128];  // 32 KB, one mat at a time
    int t = threadIdx.x;
    int colbase = blockIdx.x * 128;
    int lane = t & 63, wave = t >> 6, quad = lane >> 4, l16 = lane & 15;
    int row_base = blockIdx.y * 128 + wave * 32;
    float4v zero = {0.f, 0.f, 0.f, 0.f};
    float4v acc[2][8];
#pragma unroll
    for (int mi = 0; mi < 2; mi++)
#pragma unroll
        for (int ni = 0; ni < 8; ni++) acc[mi][ni] = zero;

    for (int mat = 0; mat < 2; mat++) {
        if (mat) __syncthreads();  // waves done reading Bs
        const u16* BT = mat ? BT2 : BT1;
        for (int c = t; c < 2048; c += 256) {
            int n = c >> 4;          // panel row 0..127
            int e = (c & 15) * 8;    // element 0..120
            int es = (e + n * 8) & 127;
            *(uint4*)&Bs[n * 128 + es] =
                *(const uint4*)(BT + (size_t)(colbase + n) * K + e);
        }
        __syncthreads();
        const u16* A = mat ? A2 : A1;
#pragma unroll
        for (int ks = 0; ks < 4; ks++) {
            int k = ks * 32 + quad * 8;
            short8 af[2] = {{0, 0, 0, 0, 0, 0, 0, 0}, {0, 0, 0, 0, 0, 0, 0, 0}};
#pragma unroll
            for (int mi = 0; mi < 2; mi++) {
                int m = row_base + mi * 16 + l16;
                if (m < M) af[mi] = *(const short8*)(A + (size_t)m * K + k);
            }
#pragma unroll
            for (int ni = 0; ni < 8; ni++) {
                int nn = ni * 16 + l16;
                int es = (k + nn * 8) & 127;
                short8 bfr = *(const short8*)&Bs[nn * 128 + es];
                acc[0][ni] = __builtin_amdgcn_mfma_f32_16x16x32_bf16(
                    af[0], bfr, acc[0][ni], 0, 0, 0);
                acc[1][ni] = __builtin_amdgcn_mfma_f32_16x16x32_bf16(
                    af[1], bfr, acc[1][ni], 0, 0, 0);
            }
        }
    }
#pragma unroll
    for (int mi = 0; mi < 2; mi++)
#pragma unroll
        for (int r = 0; r < 4; r++) {
            int row = row_base + mi * 16 + quad * 4 + r;
            if (row >= M) continue;
#pragma unroll
            for (int ni = 0; ni < 8; ni++) {
                int col = colbase + ni * 16 + l16;
                float v = acc[mi][ni][r] + bias[col];
                v = fmaxf(v, 0.f);
                out_bf[(size_t)row * N + col] = f2bf(v);
            }
        }
}

// layer 2 dual-B: pbq = fp8(hb@Wl2); out = hb@Wr2 + bl2 (fp32). K=256, N=128
__global__ __launch_bounds__(256) void gemm_l2(
    const u16* __restrict__ A, const u16* __restrict__ BT1,
    const u16* __restrict__ BT2, const float* __restrict__ bias2,
    u8* __restrict__ out1_q, float* __restrict__ out2_f, int M) {
    const int K = HID_DIM, N = OUT_DIM;
    __shared__ u16 Bs[2][128 * 128];  // 64 KB, one 128-K chunk of each B
    int t = threadIdx.x;
    int lane = t & 63, wave = t >> 6, quad = lane >> 4, l16 = lane & 15;
    int row_base = blockIdx.y * 128 + wave * 32;
    float4v zero = {0.f, 0.f, 0.f, 0.f};
    float4v acc1[2][8], acc2[2][8];
#pragma unroll
    for (int mi = 0; mi < 2; mi++)
#pragma unroll
        for (int ni = 0; ni < 8; ni++) {
            acc1[mi][ni] = zero;
            acc2[mi][ni] = zero;
        }

    for (int kc = 0; kc < 2; kc++) {
        if (kc) __syncthreads();  // compute of previous chunk done
#pragma unroll
        for (int mat = 0; mat < 2; mat++) {
            const u16* BT = mat ? BT2 : BT1;
            for (int c = t; c < 2048; c += 256) {
                int n = c >> 4;
                int e = (c & 15) * 8;
                int es = (e + n * 8) & 127;
                *(uint4*)&Bs[mat][n * 128 + es] =
                    *(const uint4*)(BT + (size_t)n * K + kc * 128 + e);
            }
        }
        __syncthreads();
#pragma unroll
        for (int ks = 0; ks < 4; ks++) {
            int k = ks * 32 + quad * 8;
            int gk = kc * 128 + k;
            short8 af[2] = {{0, 0, 0, 0, 0, 0, 0, 0}, {0, 0, 0, 0, 0, 0, 0, 0}};
#pragma unroll
            for (int mi = 0; mi < 2; mi++) {
                int m = row_base + mi * 16 + l16;
                if (m < M) af[mi] = *(const short8*)(A + (size_t)m * K + gk);
            }
#pragma unroll
            for (int ni = 0; ni < 8; ni++) {
                int nn = ni * 16 + l16;
                int es = (k + nn * 8) & 127;
                short8 b1 = *(const short8*)&Bs[0][nn * 128 + es];
                short8 b2 = *(const short8*)&Bs[1][nn * 128 + es];
                acc1[0][ni] = __builtin_amdgcn_mfma_f32_16x16x32_bf16(
                    af[0], b1, acc1[0][ni], 0, 0, 0);
                acc1[1][ni] = __builtin_amdgcn_mfma_f32_16x16x32_bf16(
                    af[1], b1, acc1[1][ni], 0, 0, 0);
                acc2[0][ni] = __builtin_amdgcn_mfma_f32_16x16x32_bf16(
                    af[0], b2, acc2[0][ni], 0, 0, 0);
                acc2[1][ni] = __builtin_amdgcn_mfma_f32_16x16x32_bf16(
                    af[1], b2, acc2[1][ni], 0, 0, 0);
            }
        }
    }
#pragma unroll
    for (int mi = 0; mi < 2; mi++)
#pragma unroll
        for (int r = 0; r < 4; r++) {
            int row = row_base + mi * 16 + quad * 4 + r;
            if (row >= M) continue;
#pragma unroll
            for (int ni = 0; ni < 8; ni++) {
                int col = ni * 16 + l16;
                out1_q[(size_t)row * N + col] = f2fp8_1(acc1[mi][ni][r]);
                out2_f[(size_t)row * N + col] = acc2[mi][ni][r] + bias2[col];
            }
        }
}

// -------------------- launcher --------------------

extern "C" void kernel_launch(void* const* d_in, const int* in_sizes, int n_in,
                              void* d_out, int out_size, void* d_ws, size_t ws_size,
                              hipStream_t stream) {
    const float* x   = (const float*)d_in[0];
    const int*  eidx = (const int*)d_in[1];
    const float* Wl1 = (const float*)d_in[2];
    const float* bl1 = (const float*)d_in[3];
    const float* Wr1 = (const float*)d_in[4];
    const float* Wl2 = (const float*)d_in[5];
    const float* bl2 = (const float*)d_in[6];
    const float* Wr2 = (const float*)d_in[7];

    int n_nodes = in_sizes[0] / IN_DIM;
    int n_edges = in_sizes[1] / 2;
    const int* src = eidx;
    const int* dst = eidx + n_edges;
    int nb = (n_nodes + 63) / 64;            // buckets of 64 nodes
    int nchunk = (n_edges + EPB - 1) / EPB;  // edge chunks (196 <= 256)

    char* p = (char*)d_ws;
    auto alloc = [&](size_t bytes) {
        void* q = (void*)p;
        p += (bytes + 255) & ~(size_t)255;
        return q;
    };
    int*   bcnt    = (int*)alloc((size_t)(nb + 1) * 4);
    int*   bbase   = (int*)alloc((size_t)(nb + 1) * 4);
    int*   cntmat  = (int*)alloc((size_t)nchunk * nb * 4);
    int*   offs    = (int*)alloc((size_t)(n_nodes + 1) * 4);
    float* inv_deg = (float*)alloc((size_t)n_nodes * 4);
    u32*   pairs   = (u32*)alloc((size_t)n_edges * 4);
    int*   csr     = (int*)alloc((size_t)n_edges * 4);
    u16*   xb      = (u16*)alloc((size_t)n_nodes * IN_DIM * 2);
    u32*   xq      = (u32*)alloc((size_t)n_nodes * IN_DIM);      // fp8
    u16*   mean1b  = (u16*)alloc((size_t)n_nodes * IN_DIM * 2);
    u16*   hb      = (u16*)alloc((size_t)n_nodes * HID_DIM * 2);
    u8*    pbq     = (u8*)alloc((size_t)n_nodes * OUT_DIM);      // fp8
    u16*   WTl1b   = (u16*)alloc((size_t)IN_DIM * HID_DIM * 2);
    u16*   WTr1b   = (u16*)alloc((size_t)IN_DIM * HID_DIM * 2);
    u16*   WTl2b   = (u16*)alloc((size_t)HID_DIM * OUT_DIM * 2);
    u16*   WTr2b   = (u16*)alloc((size_t)HID_DIM * OUT_DIM * 2);

    int n4 = n_nodes * IN_DIM / 4;
    int xblocks = (n4 + 255) / 256;
    int wblocks = (4 * 32768 + 255) / 256;

    // fused hist + casts
    hist_prep<<<nchunk + xblocks + wblocks, 256, 0, stream>>>(
        dst, n_edges, nb, nchunk, cntmat, x, xb, xq, Wl1, Wr1, Wl2, Wr2,
        WTl1b, WTr1b, WTl2b, WTr2b, n4, xblocks);

    // bucketed CSR build (no global atomics)
    colscan_par<<<nb, 256, 0, stream>>>(cntmat, nchunk, nb, bcnt);
    bucket_scan<<<1, 1024, 0, stream>>>(bcnt, nb, n_edges, bbase);
    partition2<<<nchunk, 256, 0, stream>>>(src, dst, n_edges, nb, bbase,
                                           cntmat, pairs);
    bucket_scatter<<<nb, 256, 0, stream>>>(pairs, bbase, n_nodes, n_edges,
                                           offs, inv_deg, csr);

    int gx = (n_nodes + 127) / 128;

    // layer 1
    agg_fp8<<<(n_nodes + 3) / 4, 256, 0, stream>>>(xq, offs, csr, inv_deg,
                                                   n_nodes, mean1b, nullptr);
    {
        dim3 g(HID_DIM / 128, gx);
        gemm_l1<<<g, 256, 0, stream>>>(mean1b, xb, WTl1b, WTr1b, bl1, hb,
                                       n_nodes);
    }

    // layer 2: pbq = fp8(hb@Wl2) ; d_out = hb@Wr2 + bl2  (one pass over hb)
    {
        dim3 g(1, gx);
        gemm_l2<<<g, 256, 0, stream>>>(hb, WTl2b, WTr2b, bl2, pbq,
                                       (float*)d_out, n_nodes);
    }
    // d_out += mean(pbq)
    agg_fp8<<<(n_nodes + 3) / 4, 256, 0, stream>>>((const u32*)pbq, offs, csr,
                                                   inv_deg, n_nodes, nullptr,
                                                   (float*)d_out);
}